// Round 3
// baseline (621.602 us; speedup 1.0000x reference)
//
#include <hip/hip_runtime.h>
#include <hip/hip_bf16.h>

// Problem constants
#define BB 8
#define NN 1024
#define BN 8192       // B*N
#define DD 256
#define HEADS 4
#define HD 1024       // HEADS*D
#define DSS 768
#define DTT 128
#define NE 131072     // raw edges
#define NEP (NE + BN) // + self loops

typedef __hip_bfloat16 bf16;

__device__ __forceinline__ float toF(float x){ return x; }
__device__ __forceinline__ float toF(bf16 x){ return __bfloat162float(x); }
__device__ __forceinline__ void stC(float* p, float v){ *p = v; }
__device__ __forceinline__ void stC(bf16* p, float v){ *p = __float2bfloat16(v); }
__device__ __forceinline__ float bf_lo(unsigned u){ return __uint_as_float(u << 16); }
__device__ __forceinline__ float bf_hi(unsigned u){ return __uint_as_float(u & 0xffff0000u); }

__device__ __forceinline__ float wredsum(float v){
  #pragma unroll
  for (int off = 32; off; off >>= 1) v += __shfl_xor(v, off);
  return v;
}
__device__ __forceinline__ float wredmax(float v){
  #pragma unroll
  for (int off = 32; off; off >>= 1) v = fmaxf(v, __shfl_xor(v, off));
  return v;
}

// ---------------------------------------------------------------------------
// Per-batch small vectors: textf, editp, mhavec (collapsed MHA), cvec
// MHA collapse is exact: kv rows identical -> softmax uniform -> o == vh.
// ---------------------------------------------------------------------------
__global__ __launch_bounds__(256) void perbatch_kernel(
    const float* __restrict__ text_emb, const float* __restrict__ edit_emb,
    const float* __restrict__ wt, const float* __restrict__ bt,
    const float* __restrict__ we, const float* __restrict__ be,
    const float* __restrict__ bs, const float* __restrict__ wp, const float* __restrict__ bp,
    const float* __restrict__ mha_iw, const float* __restrict__ mha_ib,
    const float* __restrict__ mha_ow, const float* __restrict__ mha_ob,
    float* __restrict__ textf, float* __restrict__ editp,
    float* __restrict__ mhavec, float* __restrict__ cvec)
{
  int b = blockIdx.x, d = threadIdx.x;
  __shared__ float stf[DD], sep[DD], svh[DD];
  float tf = bt[d];
  for (int k = 0; k < DTT; k++) tf += text_emb[b*DTT + k] * wt[k*DD + d];
  float ep = be[d];
  for (int k = 0; k < DSS; k++) ep += edit_emb[b*DSS + k] * we[k*DD + d];
  stf[d] = tf; sep[d] = ep;
  textf[b*DD + d] = tf; editp[b*DD + d] = ep;
  __syncthreads();
  float vh = mha_ib[512 + d];
  for (int k = 0; k < DD; k++) vh += stf[k] * mha_iw[(size_t)(512 + d)*DD + k];
  svh[d] = vh;
  __syncthreads();
  float mv = mha_ob[d];
  for (int j = 0; j < DD; j++) mv += svh[j] * mha_ow[(size_t)d*DD + j];
  mhavec[b*DD + d] = mv;
  // cvec = bs@wp0 + textf@wp1 + editp@wp2 + bp + editp (includes GAT1 +edit_flat)
  float cv = bp[d] + sep[d];
  for (int k = 0; k < DD; k++) cv += bs[k] * wp[(size_t)k*DD + d];
  for (int k = 0; k < DD; k++) cv += stf[k] * wp[(size_t)(DD + k)*DD + d];
  for (int k = 0; k < DD; k++) cv += sep[k] * wp[(size_t)(2*DD + k)*DD + d];
  cvec[b*DD + d] = cv;
}

// Wfull[k,d] = sum_j ws[k,j] * wp[j,d]  (fused struct->node projection weight)
__global__ __launch_bounds__(256) void wfull_kernel(
    const float* __restrict__ wsm, const float* __restrict__ wp, float* __restrict__ Wfull)
{
  int k = blockIdx.x, d = threadIdx.x;
  float acc = 0.f;
  for (int j = 0; j < DD; j++) acc += wsm[(size_t)k*DD + j] * wp[(size_t)j*DD + d];
  Wfull[(size_t)k*DD + d] = acc;
}

// ---------------------------------------------------------------------------
// Tiled GEMM: C[M,N] = A[M,K] @ B[K,N] (+bias/rowvec/relu). 64x64 tile/block.
// ---------------------------------------------------------------------------
template<typename TA, typename TB, typename TC>
__global__ __launch_bounds__(256) void gemm64(
    const TA* __restrict__ A, const TB* __restrict__ B, TC* __restrict__ C,
    int M, int N, int K,
    const float* __restrict__ bias, const float* __restrict__ rowvec, int relu)
{
  __shared__ __align__(16) float As[16][68];
  __shared__ __align__(16) float Bs[16][68];
  int tid = threadIdx.x;
  int tx = tid & 15, ty = tid >> 4;
  int row0 = blockIdx.y * 64, col0 = blockIdx.x * 64;
  float acc[4][4] = {};
  for (int k0 = 0; k0 < K; k0 += 16) {
    #pragma unroll
    for (int i = 0; i < 4; i++) {
      int idx = tid + i*256;
      int r  = idx >> 4, kka = idx & 15;
      As[kka][r] = toF(A[(size_t)(row0 + r)*K + k0 + kka]);
      int kkb = idx >> 6, cb = idx & 63;
      Bs[kkb][cb] = toF(B[(size_t)(k0 + kkb)*N + col0 + cb]);
    }
    __syncthreads();
    #pragma unroll
    for (int kk = 0; kk < 16; kk++) {
      float4 a4 = *(const float4*)&As[kk][ty*4];
      float4 b4 = *(const float4*)&Bs[kk][tx*4];
      float a[4] = {a4.x, a4.y, a4.z, a4.w};
      float b[4] = {b4.x, b4.y, b4.z, b4.w};
      #pragma unroll
      for (int i = 0; i < 4; i++)
        #pragma unroll
        for (int j = 0; j < 4; j++) acc[i][j] += a[i]*b[j];
    }
    __syncthreads();
  }
  #pragma unroll
  for (int i = 0; i < 4; i++) {
    int r = row0 + ty*4 + i;
    #pragma unroll
    for (int j = 0; j < 4; j++) {
      int c = col0 + tx*4 + j;
      float v = acc[i][j];
      if (bias)   v += bias[c];
      if (rowvec) v += rowvec[(size_t)(r >> 10)*N + c];
      if (relu)   v = fmaxf(v, 0.f);
      stC(&C[(size_t)r*N + c], v);
    }
  }
}

// a_s[n,h], a_d[n,h] from bf16 xw. One block per node, wave per head.
__global__ __launch_bounds__(256) void att_scores(
    const bf16* __restrict__ xw, const float* __restrict__ atts, const float* __restrict__ attd,
    float* __restrict__ a_s, float* __restrict__ a_d)
{
  int nrow = blockIdx.x, t = threadIdx.x;
  int h = t >> 6, l = t & 63;
  const bf16* xr = xw + (size_t)nrow*HD + h*DD;
  float ps = 0.f, pd = 0.f;
  #pragma unroll
  for (int i = 0; i < 4; i++) {
    float v = toF(xr[l + 64*i]);
    ps += v * atts[h*DD + l + 64*i];
    pd += v * attd[h*DD + l + 64*i];
  }
  ps = wredsum(ps); pd = wredsum(pd);
  if (l == 0) { a_s[nrow*4 + h] = ps; a_d[nrow*4 + h] = pd; }
}

// ---------------------------------------------------------------------------
// CSR build (dst-grouped), self-loops included (counts start at 1)
// ---------------------------------------------------------------------------
__global__ void csr_init(int* counts, int* fc) {
  int i = blockIdx.x*256 + threadIdx.x;
  if (i < BN) { counts[i] = 1; fc[i] = 0; }
}
__global__ void csr_count(const int* __restrict__ ei, int* __restrict__ counts) {
  int e = blockIdx.x*256 + threadIdx.x;
  if (e < NE) atomicAdd(&counts[ei[NE + e]], 1);
}
__global__ __launch_bounds__(1024) void scan_kernel(
    const int* __restrict__ counts, int* __restrict__ offs)
{
  __shared__ int part[1024];
  int t = threadIdx.x;
  int local[8]; int sum = 0;
  #pragma unroll
  for (int i = 0; i < 8; i++) { local[i] = sum; sum += counts[t*8 + i]; }
  part[t] = sum;
  __syncthreads();
  for (int off = 1; off < 1024; off <<= 1) {
    int v = (t >= off) ? part[t - off] : 0;
    __syncthreads();
    part[t] += v;
    __syncthreads();
  }
  int base = (t == 0) ? 0 : part[t - 1];
  #pragma unroll
  for (int i = 0; i < 8; i++) offs[t*8 + i] = base + local[i];
  if (t == 1023) offs[BN] = part[1023];
}
__global__ void csr_fill(const int* __restrict__ ei, const int* __restrict__ offs,
                         int* __restrict__ fc, int* __restrict__ csr)
{
  int idx = blockIdx.x*256 + threadIdx.x;
  if (idx < NE) {
    int sn = ei[idx], dn = ei[NE + idx];
    int p = offs[dn] + atomicAdd(&fc[dn], 1);
    csr[p] = sn;
  } else if (idx < NEP) {
    int i2 = idx - NE;
    int p = offs[i2] + atomicAdd(&fc[i2], 1);
    csr[p] = i2;
  }
}

// ---------------------------------------------------------------------------
// GAT aggregation: one block per dst node. Wave h owns head h: two-pass
// (max, then sum) softmax over incoming edges (deg >= 1 via self loop),
// then weighted channel aggregation, head-mean + bias + relu (+edit).
// ---------------------------------------------------------------------------
__global__ __launch_bounds__(256) void gat_aggregate(
    const bf16* __restrict__ xw, const float* __restrict__ a_s, const float* __restrict__ a_d,
    const int* __restrict__ offs, const int* __restrict__ csr,
    const float* __restrict__ bias, const float* __restrict__ editadd,
    float* __restrict__ xout)
{
  int i = blockIdx.x, t = threadIdx.x;
  int h = t >> 6, l = t & 63;
  int beg = offs[i], end = offs[i + 1];
  __shared__ float sacc[HD];
  float adh = a_d[i*4 + h];
  // pass 1: wave-level max then sum (head h)
  float mloc = -1e30f;
  for (int e = beg + l; e < end; e += 64) {
    float al = a_s[csr[e]*4 + h] + adh;
    al = al > 0.f ? al : 0.2f*al;
    mloc = fmaxf(mloc, al);
  }
  float mh = wredmax(mloc);                     // finite: deg >= 1
  float sloc = 0.f;
  for (int e = beg + l; e < end; e += 64) {
    float al = a_s[csr[e]*4 + h] + adh;
    al = al > 0.f ? al : 0.2f*al;
    sloc += expf(al - mh);
  }
  float inv = 1.f / wredsum(sloc);              // denom >= 1
  // pass 2: weighted aggregation; lane l covers channels l*4..l*4+3 of head h
  float acc0 = 0.f, acc1 = 0.f, acc2 = 0.f, acc3 = 0.f;
  for (int e = beg; e < end; e++) {
    int sn = csr[e];
    float al = a_s[sn*4 + h] + adh;
    al = al > 0.f ? al : 0.2f*al;
    float w = expf(al - mh) * inv;
    uint2 u = *(const uint2*)(xw + (size_t)sn*HD + h*DD + l*4);
    acc0 += w*bf_lo(u.x); acc1 += w*bf_hi(u.x);
    acc2 += w*bf_lo(u.y); acc3 += w*bf_hi(u.y);
  }
  sacc[h*DD + l*4 + 0] = acc0;
  sacc[h*DD + l*4 + 1] = acc1;
  sacc[h*DD + l*4 + 2] = acc2;
  sacc[h*DD + l*4 + 3] = acc3;
  __syncthreads();
  if (t < 64) {
    int b = i >> 10;
    #pragma unroll
    for (int j = 0; j < 4; j++) {
      int d = t*4 + j;
      float v = 0.25f*(sacc[d] + sacc[DD + d] + sacc[2*DD + d] + sacc[3*DD + d]) + bias[d];
      v = fmaxf(v, 0.f);                        // relu from reference
      if (editadd) v += editadd[b*DD + d];      // + edit_flat for next layer input
      xout[(size_t)i*DD + d] = v;
    }
  }
}

// comb = node2 + softmax2(node2.textf, node2.editp)@[textf;editp] + mhavec
__global__ __launch_bounds__(64) void comb_kernel(
    const float* __restrict__ node2, const float* __restrict__ textf,
    const float* __restrict__ editp, const float* __restrict__ mhavec,
    float* __restrict__ comb)
{
  int r = blockIdx.x, b = r >> 10, l = threadIdx.x;
  float n4[4], t4[4], e4[4];
  float s0 = 0.f, s1 = 0.f;
  #pragma unroll
  for (int i = 0; i < 4; i++) {
    int d = l + 64*i;
    float nv = node2[(size_t)r*DD + d];
    float tv = textf[b*DD + d];
    float ev = editp[b*DD + d];
    n4[i] = nv; t4[i] = tv; e4[i] = ev;
    s0 += nv*tv; s1 += nv*ev;
  }
  s0 = wredsum(s0); s1 = wredsum(s1);
  float mm = fmaxf(s0, s1);
  float e0 = expf(s0 - mm), e1 = expf(s1 - mm);
  float inv = 1.f / (e0 + e1);
  float p0 = e0*inv, p1 = e1*inv;
  #pragma unroll
  for (int i = 0; i < 4; i++) {
    int d = l + 64*i;
    comb[(size_t)r*DD + d] = n4[i] + p0*t4[i] + p1*e4[i] + mhavec[b*DD + d];
  }
}

// final heads: coords (3) + aa softmax probs (20) per row -> fp32 d_out
__global__ __launch_bounds__(64) void finals_kernel(
    const float* __restrict__ h1c, const float* __restrict__ h1a,
    const float* __restrict__ cw2, const float* __restrict__ cb2,
    const float* __restrict__ aw2, const float* __restrict__ ab2,
    float* __restrict__ out)
{
  int r = blockIdx.x, l = threadIdx.x;
  float c4[4], a4[4];
  #pragma unroll
  for (int i = 0; i < 4; i++) {
    c4[i] = h1c[(size_t)r*DD + l + 64*i];
    a4[i] = h1a[(size_t)r*DD + l + 64*i];
  }
  #pragma unroll
  for (int j = 0; j < 3; j++) {
    float p = 0.f;
    #pragma unroll
    for (int i = 0; i < 4; i++) p += c4[i] * cw2[(size_t)(l + 64*i)*3 + j];
    p = wredsum(p);
    if (l == 0) out[(size_t)r*3 + j] = p + cb2[j];
  }
  __shared__ float lg[20];
  for (int j = 0; j < 20; j++) {
    float p = 0.f;
    #pragma unroll
    for (int i = 0; i < 4; i++) p += a4[i] * aw2[(size_t)(l + 64*i)*20 + j];
    p = wredsum(p);
    if (l == 0) lg[j] = p + ab2[j];
  }
  __syncthreads();
  if (l < 20) {
    float mm = -1e30f;
    for (int j = 0; j < 20; j++) mm = fmaxf(mm, lg[j]);
    float den = 0.f;
    for (int j = 0; j < 20; j++) den += expf(lg[j] - mm);
    out[24576 + (size_t)r*20 + l] = expf(lg[l] - mm) / den;
  }
}

// ---------------------------------------------------------------------------
extern "C" void kernel_launch(void* const* d_in, const int* in_sizes, int n_in,
                              void* d_out, int out_size, void* d_ws, size_t ws_size,
                              hipStream_t stream)
{
  (void)in_sizes; (void)n_in; (void)out_size; (void)ws_size;
  const float* structure_emb = (const float*)d_in[0];
  const float* text_emb      = (const float*)d_in[1];
  const float* edit_emb      = (const float*)d_in[3];
  const float* ws_w    = (const float*)d_in[4];
  const float* bs_b    = (const float*)d_in[5];
  const float* wt_w    = (const float*)d_in[6];
  const float* bt_b    = (const float*)d_in[7];
  const float* we_w    = (const float*)d_in[8];
  const float* be_b    = (const float*)d_in[9];
  const float* wp_w    = (const float*)d_in[10];
  const float* bp_b    = (const float*)d_in[11];
  const float* g1_lin  = (const float*)d_in[12];
  const float* g1_as   = (const float*)d_in[13];
  const float* g1_ad   = (const float*)d_in[14];
  const float* g1_b    = (const float*)d_in[15];
  const float* g2_lin  = (const float*)d_in[16];
  const float* g2_as   = (const float*)d_in[17];
  const float* g2_ad   = (const float*)d_in[18];
  const float* g2_b    = (const float*)d_in[19];
  const float* mha_iw  = (const float*)d_in[20];
  const float* mha_ib  = (const float*)d_in[21];
  const float* mha_ow  = (const float*)d_in[22];
  const float* mha_ob  = (const float*)d_in[23];
  const float* cw1     = (const float*)d_in[24];
  const float* cb1     = (const float*)d_in[25];
  const float* cw2     = (const float*)d_in[26];
  const float* cb2     = (const float*)d_in[27];
  const float* aw1     = (const float*)d_in[28];
  const float* ab1     = (const float*)d_in[29];
  const float* aw2     = (const float*)d_in[30];
  const float* ab2     = (const float*)d_in[31];
  const int*  edge_index = (const int*)d_in[32];
  float* out = (float*)d_out;

  // --- compact workspace layout (~25.7 MB total) ---
  char* base = (char*)d_ws;
  float* F = (float*)base;
  float* textf  = F;                 // 2048
  float* editp  = F + 2048;          // 2048
  float* mhavec = F + 4096;          // 2048
  float* cvec   = F + 6144;          // 2048
  float* Wfull  = F + 8192;          // 196608
  float* buf1   = F + 204800;        // 2097152 (x0 -> x1e -> node2 -> comb)
  float* a_s    = F + 2301952;       // 32768
  float* a_d    = F + 2334720;       // 32768
  // fp32 region ends at float offset 2367488 (= 9,469,952 bytes, 16-aligned)
  bf16* xwb = (bf16*)(base + 9469952);        // 8192*1024 bf16 = 16 MB
  float* h1c = (float*)xwb;                    // overlays dead xw region
  float* h1a = h1c + 2097152;
  int* counts = (int*)(base + 26247168);
  int* offs   = counts + BN;
  int* fc     = offs + BN + 1;
  int* csr    = fc + BN;

  // per-batch vectors + fused projection weight
  perbatch_kernel<<<BB, 256, 0, stream>>>(text_emb, edit_emb, wt_w, bt_b, we_w, be_b,
      bs_b, wp_w, bp_b, mha_iw, mha_ib, mha_ow, mha_ob, textf, editp, mhavec, cvec);
  wfull_kernel<<<DSS, 256, 0, stream>>>(ws_w, wp_w, Wfull);

  // x0 = structure_emb @ Wfull + cvec[batch]   -> buf1
  gemm64<float, float, float><<<dim3(DD/64, BN/64), 256, 0, stream>>>(
      structure_emb, Wfull, buf1, BN, DD, DSS, nullptr, cvec, 0);

  // CSR build (shared by both GAT layers)
  csr_init<<<BN/256, 256, 0, stream>>>(counts, fc);
  csr_count<<<NE/256, 256, 0, stream>>>(edge_index, counts);
  scan_kernel<<<1, 1024, 0, stream>>>(counts, offs);
  csr_fill<<<(NEP + 255)/256, 256, 0, stream>>>(edge_index, offs, fc, csr);

  // GAT layer 1: xw1 = x0 @ g1_lin (bf16 out); agg -> x1e (reuses buf1)
  gemm64<float, float, bf16><<<dim3(HD/64, BN/64), 256, 0, stream>>>(
      buf1, g1_lin, xwb, BN, HD, DD, nullptr, nullptr, 0);
  att_scores<<<BN, 256, 0, stream>>>(xwb, g1_as, g1_ad, a_s, a_d);
  gat_aggregate<<<BN, 256, 0, stream>>>(xwb, a_s, a_d, offs, csr, g1_b, editp, buf1);

  // GAT layer 2: xw2 = x1e @ g2_lin; agg -> node2 (reuses buf1)
  gemm64<float, float, bf16><<<dim3(HD/64, BN/64), 256, 0, stream>>>(
      buf1, g2_lin, xwb, BN, HD, DD, nullptr, nullptr, 0);
  att_scores<<<BN, 256, 0, stream>>>(xwb, g2_as, g2_ad, a_s, a_d);
  gat_aggregate<<<BN, 256, 0, stream>>>(xwb, a_s, a_d, offs, csr, g2_b, nullptr, buf1);

  // comb = node2 + global-attn(2-token) + mhavec   (in place in buf1)
  comb_kernel<<<BN, 64, 0, stream>>>(buf1, textf, editp, mhavec, buf1);

  // heads (write into dead xw region)
  gemm64<float, float, float><<<dim3(DD/64, BN/64), 256, 0, stream>>>(
      buf1, cw1, h1c, BN, DD, DD, cb1, nullptr, 1);
  gemm64<float, float, float><<<dim3(DD/64, BN/64), 256, 0, stream>>>(
      buf1, aw1, h1a, BN, DD, DD, ab1, nullptr, 1);
  finals_kernel<<<BN, 64, 0, stream>>>(h1c, h1a, cw2, cb2, aw2, ab2, out);
}

// Round 4
// 439.997 us; speedup vs baseline: 1.4127x; 1.4127x over previous
//
#include <hip/hip_runtime.h>
#include <hip/hip_bf16.h>

// Problem constants
#define BB 8
#define NN 1024
#define BN 8192       // B*N
#define DD 256
#define HEADS 4
#define HD 1024       // HEADS*D
#define DSS 768
#define DTT 128
#define NE 131072     // raw edges
#define NEP (NE + BN) // + self loops

typedef __hip_bfloat16 bf16;
typedef __attribute__((ext_vector_type(8))) short short8;   // 8 bf16 (4 VGPRs)
typedef __attribute__((ext_vector_type(4))) float floatx4;  // MFMA C/D

__device__ __forceinline__ float toF(bf16 x){ return __bfloat162float(x); }
__device__ __forceinline__ void stC(float* p, float v){ *p = v; }
__device__ __forceinline__ void stC(bf16* p, float v){ *p = __float2bfloat16(v); }
__device__ __forceinline__ float bf_lo(unsigned u){ return __uint_as_float(u << 16); }
__device__ __forceinline__ float bf_hi(unsigned u){ return __uint_as_float(u & 0xffff0000u); }

__device__ __forceinline__ float wredsum(float v){
  #pragma unroll
  for (int off = 32; off; off >>= 1) v += __shfl_xor(v, off);
  return v;
}
__device__ __forceinline__ float wredmax(float v){
  #pragma unroll
  for (int off = 32; off; off >>= 1) v = fmaxf(v, __shfl_xor(v, off));
  return v;
}

// ---------------------------------------------------------------------------
// Per-batch small vectors (parallelized: round-3 perbatch was 88us @0.3% occ)
// ---------------------------------------------------------------------------
// textf[b,d] = bt[d] + text_emb[b]@wt[:,d];  editp likewise (grid (8,4), 256thr)
__global__ __launch_bounds__(256) void pk_textedit(
    const float* __restrict__ text_emb, const float* __restrict__ edit_emb,
    const float* __restrict__ wt, const float* __restrict__ bt,
    const float* __restrict__ we, const float* __restrict__ be,
    float* __restrict__ textf, float* __restrict__ editp)
{
  int b = blockIdx.x, l = threadIdx.x & 63, qq = threadIdx.x >> 6;
  int d = blockIdx.y*64 + l;
  __shared__ float red[2][4][64];
  float tf = 0.f;
  for (int k = qq*32; k < qq*32 + 32; k++) tf += text_emb[b*DTT + k] * wt[(size_t)k*DD + d];
  float ep = 0.f;
  for (int k = qq*192; k < qq*192 + 192; k++) ep += edit_emb[b*DSS + k] * we[(size_t)k*DD + d];
  red[0][qq][l] = tf; red[1][qq][l] = ep;
  __syncthreads();
  if (threadIdx.x < 64) {
    int dd = blockIdx.y*64 + threadIdx.x;
    textf[b*DD + dd] = red[0][0][threadIdx.x]+red[0][1][threadIdx.x]+red[0][2][threadIdx.x]+red[0][3][threadIdx.x] + bt[dd];
    editp[b*DD + dd] = red[1][0][threadIdx.x]+red[1][1][threadIdx.x]+red[1][2][threadIdx.x]+red[1][3][threadIdx.x] + be[dd];
  }
}

// vh[b,d] = mha_ib[512+d] + textf[b]@mha_iw[512+d,:]   (grid (8,64), wave/dot)
__global__ __launch_bounds__(256) void pk_vh(
    const float* __restrict__ textf, const float* __restrict__ mha_iw,
    const float* __restrict__ mha_ib, float* __restrict__ vh)
{
  int b = blockIdx.x, w = threadIdx.x >> 6, l = threadIdx.x & 63;
  int d = blockIdx.y*4 + w;
  float p = 0.f;
  #pragma unroll
  for (int i = 0; i < 4; i++) p += textf[b*DD + l + 64*i] * mha_iw[(size_t)(512 + d)*DD + l + 64*i];
  p = wredsum(p);
  if (l == 0) vh[b*DD + d] = p + mha_ib[512 + d];
}

// mhavec[b,d] = mha_ob[d] + vh[b]@mha_ow[d,:]   (exact collapsed MHA)
__global__ __launch_bounds__(256) void pk_mhavec(
    const float* __restrict__ vh, const float* __restrict__ mha_ow,
    const float* __restrict__ mha_ob, float* __restrict__ mhavec)
{
  int b = blockIdx.x, w = threadIdx.x >> 6, l = threadIdx.x & 63;
  int d = blockIdx.y*4 + w;
  float p = 0.f;
  #pragma unroll
  for (int i = 0; i < 4; i++) p += vh[b*DD + l + 64*i] * mha_ow[(size_t)d*DD + l + 64*i];
  p = wredsum(p);
  if (l == 0) mhavec[b*DD + d] = p + mha_ob[d];
}

// cvec = bs@wp0 + textf@wp1 + editp@wp2 + bp + editp   (grid (8,4))
__global__ __launch_bounds__(256) void pk_cvec(
    const float* __restrict__ textf, const float* __restrict__ editp,
    const float* __restrict__ bs, const float* __restrict__ wp, const float* __restrict__ bp,
    float* __restrict__ cvec)
{
  int b = blockIdx.x, l = threadIdx.x & 63, qq = threadIdx.x >> 6;
  int d = blockIdx.y*64 + l;
  __shared__ float red[4][64];
  float cv = 0.f;
  for (int k = qq*64; k < qq*64 + 64; k++) cv += bs[k] * wp[(size_t)k*DD + d];
  for (int k = qq*64; k < qq*64 + 64; k++) cv += textf[b*DD + k] * wp[(size_t)(DD + k)*DD + d];
  for (int k = qq*64; k < qq*64 + 64; k++) cv += editp[b*DD + k] * wp[(size_t)(2*DD + k)*DD + d];
  red[qq][l] = cv;
  __syncthreads();
  if (threadIdx.x < 64) {
    int dd = blockIdx.y*64 + threadIdx.x;
    cvec[b*DD + dd] = red[0][threadIdx.x]+red[1][threadIdx.x]+red[2][threadIdx.x]+red[3][threadIdx.x]
                      + bp[dd] + editp[b*DD + dd];
  }
}

// WfullT[d][k] = sum_j ws[k,j]*wp[j,d]  -> bf16 [256][768]  (grid 96, 8 k/block)
__global__ __launch_bounds__(256) void wfullT_kernel(
    const float* __restrict__ wsm, const float* __restrict__ wp, bf16* __restrict__ WT)
{
  int k0 = blockIdx.x*8, d = threadIdx.x;
  float acc[8] = {};
  for (int j = 0; j < DD; j++) {
    float wv = wp[(size_t)j*DD + d];
    #pragma unroll
    for (int kk = 0; kk < 8; kk++) acc[kk] += wsm[(size_t)(k0 + kk)*DD + j] * wv;
  }
  #pragma unroll
  for (int kk = 0; kk < 8; kk++) WT[(size_t)d*DSS + k0 + kk] = __float2bfloat16(acc[kk]);
}

// fp32 -> bf16 copy (n multiple of 1024)
__global__ __launch_bounds__(256) void conv_bf16(
    const float* __restrict__ src, bf16* __restrict__ dst)
{
  int i = (blockIdx.x*256 + threadIdx.x)*4;
  float4 v = *(const float4*)(src + i);
  bf16 t[4] = {__float2bfloat16(v.x), __float2bfloat16(v.y),
               __float2bfloat16(v.z), __float2bfloat16(v.w)};
  *(uint2*)(dst + i) = *(uint2*)t;
}

// dst[c][r] = bf16(src[r][c]);  grid (C/32, R/32), 256 thr
__global__ __launch_bounds__(256) void transpose_bf16(
    const float* __restrict__ src, bf16* __restrict__ dst, int R, int C)
{
  __shared__ float t[32][33];
  int c0 = blockIdx.x*32, r0 = blockIdx.y*32;
  int tr = threadIdx.x >> 5, tc = threadIdx.x & 31;
  #pragma unroll
  for (int i = 0; i < 4; i++)
    t[tr + i*8][tc] = src[(size_t)(r0 + tr + i*8)*C + c0 + tc];
  __syncthreads();
  #pragma unroll
  for (int i = 0; i < 4; i++)
    dst[(size_t)(c0 + tr + i*8)*R + r0 + tc] = __float2bfloat16(t[tc][tr + i*8]);
}

// ---------------------------------------------------------------------------
// MFMA GEMM: C[M,N] = A[M,K] @ Bt[N,K]^T, bf16 in, fp32 acc.
// 64x64 tile/block (4 waves), BK=64. Layouts per m89/m91/m120:
//   A-frag: m=lane&15, k=(lane>>4)*8+j ; B-frag: n=lane&15, same k
//   C/D:    col=lane&15, row=(lane>>4)*4+reg
// ---------------------------------------------------------------------------
template<typename TC>
__global__ __launch_bounds__(256) void gemm_mfma(
    const bf16* __restrict__ A, const bf16* __restrict__ Bt, TC* __restrict__ C,
    int M, int N, int K,
    const float* __restrict__ bias, const float* __restrict__ rowvec, int relu)
{
  __shared__ __align__(16) bf16 Asl[64*72];  // row stride 72 bf16 (=36 words)
  __shared__ __align__(16) bf16 Bsl[64*72];
  int tid = threadIdx.x;
  int w = tid >> 6, lane = tid & 63;
  int q = lane >> 4, mn = lane & 15;
  int row0 = blockIdx.y*64, col0 = blockIdx.x*64;
  int sr = tid >> 3, sc = tid & 7;             // staging: 32 rows x 8 chunks/pass
  floatx4 acc[4];
  #pragma unroll
  for (int t = 0; t < 4; t++) acc[t] = (floatx4){0.f, 0.f, 0.f, 0.f};

  for (int k0 = 0; k0 < K; k0 += 64) {
    uint4 a0 = *(const uint4*)(A  + (size_t)(row0 + sr)*K      + k0 + sc*8);
    uint4 a1 = *(const uint4*)(A  + (size_t)(row0 + 32 + sr)*K + k0 + sc*8);
    uint4 b0 = *(const uint4*)(Bt + (size_t)(col0 + sr)*K      + k0 + sc*8);
    uint4 b1 = *(const uint4*)(Bt + (size_t)(col0 + 32 + sr)*K + k0 + sc*8);
    __syncthreads();                            // LDS reads of prev iter done
    *(uint4*)&Asl[sr*72 + sc*8]        = a0;
    *(uint4*)&Asl[(sr + 32)*72 + sc*8] = a1;
    *(uint4*)&Bsl[sr*72 + sc*8]        = b0;
    *(uint4*)&Bsl[(sr + 32)*72 + sc*8] = b1;
    __syncthreads();
    #pragma unroll
    for (int kk = 0; kk < 64; kk += 32) {
      short8 af = *(const short8*)&Asl[(w*16 + mn)*72 + kk + q*8];
      #pragma unroll
      for (int t = 0; t < 4; t++) {
        short8 bfr = *(const short8*)&Bsl[(t*16 + mn)*72 + kk + q*8];
        acc[t] = __builtin_amdgcn_mfma_f32_16x16x32_bf16(af, bfr, acc[t], 0, 0, 0);
      }
    }
  }
  #pragma unroll
  for (int t = 0; t < 4; t++) {
    #pragma unroll
    for (int rg = 0; rg < 4; rg++) {
      int r = row0 + w*16 + q*4 + rg;
      int c = col0 + t*16 + mn;
      float v = acc[t][rg];
      if (bias)   v += bias[c];
      if (rowvec) v += rowvec[(size_t)(r >> 10)*N + c];
      if (relu)   v = fmaxf(v, 0.f);
      stC(&C[(size_t)r*N + c], v);
    }
  }
}

// a_s[n,h], a_d[n,h] from bf16 xw. One block per node, wave per head.
__global__ __launch_bounds__(256) void att_scores(
    const bf16* __restrict__ xw, const float* __restrict__ atts, const float* __restrict__ attd,
    float* __restrict__ a_s, float* __restrict__ a_d)
{
  int nrow = blockIdx.x, t = threadIdx.x;
  int h = t >> 6, l = t & 63;
  const bf16* xr = xw + (size_t)nrow*HD + h*DD;
  float ps = 0.f, pd = 0.f;
  #pragma unroll
  for (int i = 0; i < 4; i++) {
    float v = toF(xr[l + 64*i]);
    ps += v * atts[h*DD + l + 64*i];
    pd += v * attd[h*DD + l + 64*i];
  }
  ps = wredsum(ps); pd = wredsum(pd);
  if (l == 0) { a_s[nrow*4 + h] = ps; a_d[nrow*4 + h] = pd; }
}

// ---------------------------------------------------------------------------
// CSR build (dst-grouped), self-loops included (counts start at 1)
// ---------------------------------------------------------------------------
__global__ void csr_init(int* counts, int* fc) {
  int i = blockIdx.x*256 + threadIdx.x;
  if (i < BN) { counts[i] = 1; fc[i] = 0; }
}
__global__ void csr_count(const int* __restrict__ ei, int* __restrict__ counts) {
  int e = blockIdx.x*256 + threadIdx.x;
  if (e < NE) atomicAdd(&counts[ei[NE + e]], 1);
}
__global__ __launch_bounds__(1024) void scan_kernel(
    const int* __restrict__ counts, int* __restrict__ offs)
{
  __shared__ int part[1024];
  int t = threadIdx.x;
  int local[8]; int sum = 0;
  #pragma unroll
  for (int i = 0; i < 8; i++) { local[i] = sum; sum += counts[t*8 + i]; }
  part[t] = sum;
  __syncthreads();
  for (int off = 1; off < 1024; off <<= 1) {
    int v = (t >= off) ? part[t - off] : 0;
    __syncthreads();
    part[t] += v;
    __syncthreads();
  }
  int base = (t == 0) ? 0 : part[t - 1];
  #pragma unroll
  for (int i = 0; i < 8; i++) offs[t*8 + i] = base + local[i];
  if (t == 1023) offs[BN] = part[1023];
}
__global__ void csr_fill(const int* __restrict__ ei, const int* __restrict__ offs,
                         int* __restrict__ fc, int* __restrict__ csr)
{
  int idx = blockIdx.x*256 + threadIdx.x;
  if (idx < NE) {
    int sn = ei[idx], dn = ei[NE + idx];
    int p = offs[dn] + atomicAdd(&fc[dn], 1);
    csr[p] = sn;
  } else if (idx < NEP) {
    int i2 = idx - NE;
    int p = offs[i2] + atomicAdd(&fc[i2], 1);
    csr[p] = i2;
  }
}

// ---------------------------------------------------------------------------
// GAT aggregation: block per dst node, wave per head; two-pass softmax +
// weighted channel aggregation; head-mean + bias + relu (+edit). bf16 out.
// ---------------------------------------------------------------------------
__global__ __launch_bounds__(256) void gat_aggregate(
    const bf16* __restrict__ xw, const float* __restrict__ a_s, const float* __restrict__ a_d,
    const int* __restrict__ offs, const int* __restrict__ csr,
    const float* __restrict__ bias, const float* __restrict__ editadd,
    bf16* __restrict__ xout)
{
  int i = blockIdx.x, t = threadIdx.x;
  int h = t >> 6, l = t & 63;
  int beg = offs[i], end = offs[i + 1];
  __shared__ float sacc[HD];
  float adh = a_d[i*4 + h];
  float mloc = -1e30f;
  for (int e = beg + l; e < end; e += 64) {
    float al = a_s[csr[e]*4 + h] + adh;
    al = al > 0.f ? al : 0.2f*al;
    mloc = fmaxf(mloc, al);
  }
  float mh = wredmax(mloc);                     // finite: deg >= 1
  float sloc = 0.f;
  for (int e = beg + l; e < end; e += 64) {
    float al = a_s[csr[e]*4 + h] + adh;
    al = al > 0.f ? al : 0.2f*al;
    sloc += expf(al - mh);
  }
  float inv = 1.f / wredsum(sloc);              // denom >= 1
  float acc0 = 0.f, acc1 = 0.f, acc2 = 0.f, acc3 = 0.f;
  for (int e = beg; e < end; e++) {
    int sn = csr[e];
    float al = a_s[sn*4 + h] + adh;
    al = al > 0.f ? al : 0.2f*al;
    float w = expf(al - mh) * inv;
    uint2 u = *(const uint2*)(xw + (size_t)sn*HD + h*DD + l*4);
    acc0 += w*bf_lo(u.x); acc1 += w*bf_hi(u.x);
    acc2 += w*bf_lo(u.y); acc3 += w*bf_hi(u.y);
  }
  sacc[h*DD + l*4 + 0] = acc0;
  sacc[h*DD + l*4 + 1] = acc1;
  sacc[h*DD + l*4 + 2] = acc2;
  sacc[h*DD + l*4 + 3] = acc3;
  __syncthreads();
  if (t < 64) {
    int b = i >> 10;
    #pragma unroll
    for (int j = 0; j < 4; j++) {
      int d = t*4 + j;
      float v = 0.25f*(sacc[d] + sacc[DD + d] + sacc[2*DD + d] + sacc[3*DD + d]) + bias[d];
      v = fmaxf(v, 0.f);
      if (editadd) v += editadd[b*DD + d];
      xout[(size_t)i*DD + d] = __float2bfloat16(v);
    }
  }
}

// comb = node2 + softmax2(node2.textf, node2.editp)@[textf;editp] + mhavec
// in place on bf16 node buffer
__global__ __launch_bounds__(64) void comb_kernel(
    bf16* __restrict__ nodeb, const float* __restrict__ textf,
    const float* __restrict__ editp, const float* __restrict__ mhavec)
{
  int r = blockIdx.x, b = r >> 10, l = threadIdx.x;
  float n4[4], t4[4], e4[4];
  float s0 = 0.f, s1 = 0.f;
  #pragma unroll
  for (int i = 0; i < 4; i++) {
    int d = l + 64*i;
    float nv = toF(nodeb[(size_t)r*DD + d]);
    float tv = textf[b*DD + d];
    float ev = editp[b*DD + d];
    n4[i] = nv; t4[i] = tv; e4[i] = ev;
    s0 += nv*tv; s1 += nv*ev;
  }
  s0 = wredsum(s0); s1 = wredsum(s1);
  float mm = fmaxf(s0, s1);
  float e0 = expf(s0 - mm), e1 = expf(s1 - mm);
  float inv = 1.f / (e0 + e1);
  float p0 = e0*inv, p1 = e1*inv;
  #pragma unroll
  for (int i = 0; i < 4; i++) {
    int d = l + 64*i;
    nodeb[(size_t)r*DD + d] = __float2bfloat16(n4[i] + p0*t4[i] + p1*e4[i] + mhavec[b*DD + d]);
  }
}

// final heads: coords (3) + aa softmax probs (20) per row -> fp32 d_out
__global__ __launch_bounds__(64) void finals_kernel(
    const float* __restrict__ h1c, const float* __restrict__ h1a,
    const float* __restrict__ cw2, const float* __restrict__ cb2,
    const float* __restrict__ aw2, const float* __restrict__ ab2,
    float* __restrict__ out)
{
  int r = blockIdx.x, l = threadIdx.x;
  float c4[4], a4[4];
  #pragma unroll
  for (int i = 0; i < 4; i++) {
    c4[i] = h1c[(size_t)r*DD + l + 64*i];
    a4[i] = h1a[(size_t)r*DD + l + 64*i];
  }
  #pragma unroll
  for (int j = 0; j < 3; j++) {
    float p = 0.f;
    #pragma unroll
    for (int i = 0; i < 4; i++) p += c4[i] * cw2[(size_t)(l + 64*i)*3 + j];
    p = wredsum(p);
    if (l == 0) out[(size_t)r*3 + j] = p + cb2[j];
  }
  __shared__ float lg[20];
  for (int j = 0; j < 20; j++) {
    float p = 0.f;
    #pragma unroll
    for (int i = 0; i < 4; i++) p += a4[i] * aw2[(size_t)(l + 64*i)*20 + j];
    p = wredsum(p);
    if (l == 0) lg[j] = p + ab2[j];
  }
  __syncthreads();
  if (l < 20) {
    float mm = -1e30f;
    for (int j = 0; j < 20; j++) mm = fmaxf(mm, lg[j]);
    float den = 0.f;
    for (int j = 0; j < 20; j++) den += expf(lg[j] - mm);
    out[24576 + (size_t)r*20 + l] = expf(lg[l] - mm) / den;
  }
}

// ---------------------------------------------------------------------------
extern "C" void kernel_launch(void* const* d_in, const int* in_sizes, int n_in,
                              void* d_out, int out_size, void* d_ws, size_t ws_size,
                              hipStream_t stream)
{
  (void)in_sizes; (void)n_in; (void)out_size; (void)ws_size;
  const float* structure_emb = (const float*)d_in[0];
  const float* text_emb      = (const float*)d_in[1];
  const float* edit_emb      = (const float*)d_in[3];
  const float* ws_w    = (const float*)d_in[4];
  const float* bs_b    = (const float*)d_in[5];
  const float* wt_w    = (const float*)d_in[6];
  const float* bt_b    = (const float*)d_in[7];
  const float* we_w    = (const float*)d_in[8];
  const float* be_b    = (const float*)d_in[9];
  const float* wp_w    = (const float*)d_in[10];
  const float* bp_b    = (const float*)d_in[11];
  const float* g1_lin  = (const float*)d_in[12];
  const float* g1_as   = (const float*)d_in[13];
  const float* g1_ad   = (const float*)d_in[14];
  const float* g1_b    = (const float*)d_in[15];
  const float* g2_lin  = (const float*)d_in[16];
  const float* g2_as   = (const float*)d_in[17];
  const float* g2_ad   = (const float*)d_in[18];
  const float* g2_b    = (const float*)d_in[19];
  const float* mha_iw  = (const float*)d_in[20];
  const float* mha_ib  = (const float*)d_in[21];
  const float* mha_ow  = (const float*)d_in[22];
  const float* mha_ob  = (const float*)d_in[23];
  const float* cw1     = (const float*)d_in[24];
  const float* cb1     = (const float*)d_in[25];
  const float* cw2     = (const float*)d_in[26];
  const float* cb2     = (const float*)d_in[27];
  const float* aw1     = (const float*)d_in[28];
  const float* ab1     = (const float*)d_in[29];
  const float* aw2     = (const float*)d_in[30];
  const float* ab2     = (const float*)d_in[31];
  const int*  edge_index = (const int*)d_in[32];
  float* out = (float*)d_out;

  // --- workspace layout (~22.6 MB) ---
  char* p = (char*)d_ws;
  // 16 MB big region, time-multiplexed: sembB (12.6MB) -> xwb (16MB) -> h1c+h1a (16MB)
  bf16*  sembB = (bf16*)p;
  bf16*  xwb   = (bf16*)p;
  float* h1c   = (float*)p;
  float* h1a   = (float*)(p + 8388608);
  p += 16777216;
  bf16* bufB = (bf16*)p; p += 4194304;   // [8192][256] bf16: x0 -> x1e -> node2 -> comb
  bf16* g1T  = (bf16*)p; p += 524288;    // [1024][256]
  bf16* g2T  = (bf16*)p; p += 524288;
  bf16* cw1T = (bf16*)p; p += 131072;    // [256][256]
  bf16* aw1T = (bf16*)p; p += 131072;
  bf16* WfT  = (bf16*)p; p += 393216;    // [256][768]
  float* textf  = (float*)p; p += 8192;
  float* editp  = (float*)p; p += 8192;
  float* vhws   = (float*)p; p += 8192;
  float* mhavec = (float*)p; p += 8192;
  float* cvec   = (float*)p; p += 8192;
  float* a_s    = (float*)p; p += 131072;
  float* a_d    = (float*)p; p += 131072;
  int* counts = (int*)p; p += 32768;
  int* offs   = (int*)p; p += 32784;     // BN+1, padded
  int* fc     = (int*)p; p += 32768;
  int* csr    = (int*)p; p += NEP*4;

  // per-batch vectors (parallelized)
  pk_textedit<<<dim3(BB,4), 256, 0, stream>>>(text_emb, edit_emb, wt_w, bt_b, we_w, be_b, textf, editp);
  wfullT_kernel<<<96, 256, 0, stream>>>(ws_w, wp_w, WfT);
  pk_vh<<<dim3(BB,64), 256, 0, stream>>>(textf, mha_iw, mha_ib, vhws);
  pk_mhavec<<<dim3(BB,64), 256, 0, stream>>>(vhws, mha_ow, mha_ob, mhavec);
  pk_cvec<<<dim3(BB,4), 256, 0, stream>>>(textf, editp, bs_b, wp_w, bp_b, cvec);

  // weight/input conversions for MFMA
  conv_bf16<<<(BN*DSS)/1024, 256, 0, stream>>>(structure_emb, sembB);
  transpose_bf16<<<dim3(32,8), 256, 0, stream>>>(g1_lin, g1T, DD, HD);
  transpose_bf16<<<dim3(32,8), 256, 0, stream>>>(g2_lin, g2T, DD, HD);
  transpose_bf16<<<dim3(8,8),  256, 0, stream>>>(cw1, cw1T, DD, DD);
  transpose_bf16<<<dim3(8,8),  256, 0, stream>>>(aw1, aw1T, DD, DD);

  // CSR build (shared by both GAT layers)
  csr_init<<<BN/256, 256, 0, stream>>>(counts, fc);
  csr_count<<<NE/256, 256, 0, stream>>>(edge_index, counts);
  scan_kernel<<<1, 1024, 0, stream>>>(counts, offs);
  csr_fill<<<(NEP + 255)/256, 256, 0, stream>>>(edge_index, offs, fc, csr);

  // x0 = semb @ Wfull + cvec[batch]  -> bufB (bf16)
  gemm_mfma<bf16><<<dim3(DD/64, BN/64), 256, 0, stream>>>(
      sembB, WfT, bufB, BN, DD, DSS, nullptr, cvec, 0);

  // GAT layer 1
  gemm_mfma<bf16><<<dim3(HD/64, BN/64), 256, 0, stream>>>(
      bufB, g1T, xwb, BN, HD, DD, nullptr, nullptr, 0);
  att_scores<<<BN, 256, 0, stream>>>(xwb, g1_as, g1_ad, a_s, a_d);
  gat_aggregate<<<BN, 256, 0, stream>>>(xwb, a_s, a_d, offs, csr, g1_b, editp, bufB);

  // GAT layer 2
  gemm_mfma<bf16><<<dim3(HD/64, BN/64), 256, 0, stream>>>(
      bufB, g2T, xwb, BN, HD, DD, nullptr, nullptr, 0);
  att_scores<<<BN, 256, 0, stream>>>(xwb, g2_as, g2_ad, a_s, a_d);
  gat_aggregate<<<BN, 256, 0, stream>>>(xwb, a_s, a_d, offs, csr, g2_b, nullptr, bufB);

  // comb (in place on bufB)
  comb_kernel<<<BN, 64, 0, stream>>>(bufB, textf, editp, mhavec);

  // heads (h1c/h1a overlay the dead xw region)
  gemm_mfma<float><<<dim3(DD/64, BN/64), 256, 0, stream>>>(
      bufB, cw1T, h1c, BN, DD, DD, cb1, nullptr, 1);
  gemm_mfma<float><<<dim3(DD/64, BN/64), 256, 0, stream>>>(
      bufB, aw1T, h1a, BN, DD, DD, ab1, nullptr, 1);
  finals_kernel<<<BN, 64, 0, stream>>>(h1c, h1a, cw2, cb2, aw2, ab2, out);
}

// Round 5
// 409.253 us; speedup vs baseline: 1.5189x; 1.0751x over previous
//
#include <hip/hip_runtime.h>
#include <hip/hip_bf16.h>

// Problem constants
#define BB 8
#define NN 1024
#define BN 8192       // B*N
#define DD 256
#define HEADS 4
#define HD 1024       // HEADS*D
#define DSS 768
#define DTT 128
#define NE 131072     // raw edges
#define NEP (NE + BN) // + self loops
#define DEGCAP 256    // LDS-cached edges per node (max in-degree ~40 for this input)

typedef __hip_bfloat16 bf16;
typedef __attribute__((ext_vector_type(8))) short short8;   // 8 bf16 (4 VGPRs)
typedef __attribute__((ext_vector_type(4))) float floatx4;  // MFMA C/D

__device__ __forceinline__ float toF(bf16 x){ return __bfloat162float(x); }
__device__ __forceinline__ void stC(float* p, float v){ *p = v; }
__device__ __forceinline__ void stC(bf16* p, float v){ *p = __float2bfloat16(v); }
__device__ __forceinline__ float bf_lo(unsigned u){ return __uint_as_float(u << 16); }
__device__ __forceinline__ float bf_hi(unsigned u){ return __uint_as_float(u & 0xffff0000u); }

__device__ __forceinline__ float wredsum(float v){
  #pragma unroll
  for (int off = 32; off; off >>= 1) v += __shfl_xor(v, off);
  return v;
}
__device__ __forceinline__ float wredmax(float v){
  #pragma unroll
  for (int off = 32; off; off >>= 1) v = fmaxf(v, __shfl_xor(v, off));
  return v;
}

// ---------------------------------------------------------------------------
// Per-batch small vectors (parallelized)
// ---------------------------------------------------------------------------
__global__ __launch_bounds__(256) void pk_textedit(
    const float* __restrict__ text_emb, const float* __restrict__ edit_emb,
    const float* __restrict__ wt, const float* __restrict__ bt,
    const float* __restrict__ we, const float* __restrict__ be,
    float* __restrict__ textf, float* __restrict__ editp)
{
  int b = blockIdx.x, l = threadIdx.x & 63, qq = threadIdx.x >> 6;
  int d = blockIdx.y*64 + l;
  __shared__ float red[2][4][64];
  float tf = 0.f;
  for (int k = qq*32; k < qq*32 + 32; k++) tf += text_emb[b*DTT + k] * wt[(size_t)k*DD + d];
  float ep = 0.f;
  for (int k = qq*192; k < qq*192 + 192; k++) ep += edit_emb[b*DSS + k] * we[(size_t)k*DD + d];
  red[0][qq][l] = tf; red[1][qq][l] = ep;
  __syncthreads();
  if (threadIdx.x < 64) {
    int dd = blockIdx.y*64 + threadIdx.x;
    textf[b*DD + dd] = red[0][0][threadIdx.x]+red[0][1][threadIdx.x]+red[0][2][threadIdx.x]+red[0][3][threadIdx.x] + bt[dd];
    editp[b*DD + dd] = red[1][0][threadIdx.x]+red[1][1][threadIdx.x]+red[1][2][threadIdx.x]+red[1][3][threadIdx.x] + be[dd];
  }
}

// vh[b,d] = mha_ib[512+d] + textf[b]@mha_iw[512+d,:]   (grid (8,64), wave/dot)
__global__ __launch_bounds__(256) void pk_vh(
    const float* __restrict__ textf, const float* __restrict__ mha_iw,
    const float* __restrict__ mha_ib, float* __restrict__ vh)
{
  int b = blockIdx.x, w = threadIdx.x >> 6, l = threadIdx.x & 63;
  int d = blockIdx.y*4 + w;
  float p = 0.f;
  #pragma unroll
  for (int i = 0; i < 4; i++) p += textf[b*DD + l + 64*i] * mha_iw[(size_t)(512 + d)*DD + l + 64*i];
  p = wredsum(p);
  if (l == 0) vh[b*DD + d] = p + mha_ib[512 + d];
}

// mhavec[b,d] = mha_ob[d] + vh[b]@mha_ow[d,:]   (exact collapsed MHA)
__global__ __launch_bounds__(256) void pk_mhavec(
    const float* __restrict__ vh, const float* __restrict__ mha_ow,
    const float* __restrict__ mha_ob, float* __restrict__ mhavec)
{
  int b = blockIdx.x, w = threadIdx.x >> 6, l = threadIdx.x & 63;
  int d = blockIdx.y*4 + w;
  float p = 0.f;
  #pragma unroll
  for (int i = 0; i < 4; i++) p += vh[b*DD + l + 64*i] * mha_ow[(size_t)d*DD + l + 64*i];
  p = wredsum(p);
  if (l == 0) mhavec[b*DD + d] = p + mha_ob[d];
}

// cvec = bs@wp0 + textf@wp1 + editp@wp2 + bp + editp   (grid (8,4))
__global__ __launch_bounds__(256) void pk_cvec(
    const float* __restrict__ textf, const float* __restrict__ editp,
    const float* __restrict__ bs, const float* __restrict__ wp, const float* __restrict__ bp,
    float* __restrict__ cvec)
{
  int b = blockIdx.x, l = threadIdx.x & 63, qq = threadIdx.x >> 6;
  int d = blockIdx.y*64 + l;
  __shared__ float red[4][64];
  float cv = 0.f;
  for (int k = qq*64; k < qq*64 + 64; k++) cv += bs[k] * wp[(size_t)k*DD + d];
  for (int k = qq*64; k < qq*64 + 64; k++) cv += textf[b*DD + k] * wp[(size_t)(DD + k)*DD + d];
  for (int k = qq*64; k < qq*64 + 64; k++) cv += editp[b*DD + k] * wp[(size_t)(2*DD + k)*DD + d];
  red[qq][l] = cv;
  __syncthreads();
  if (threadIdx.x < 64) {
    int dd = blockIdx.y*64 + threadIdx.x;
    cvec[b*DD + dd] = red[0][threadIdx.x]+red[1][threadIdx.x]+red[2][threadIdx.x]+red[3][threadIdx.x]
                      + bp[dd] + editp[b*DD + dd];
  }
}

// WfullT[d][k] = sum_j ws[k,j]*wp[j,d]  -> bf16 [256][768]  (grid 96)
__global__ __launch_bounds__(256) void wfullT_kernel(
    const float* __restrict__ wsm, const float* __restrict__ wp, bf16* __restrict__ WT)
{
  int k0 = blockIdx.x*8, d = threadIdx.x;
  float acc[8] = {};
  for (int j = 0; j < DD; j++) {
    float wv = wp[(size_t)j*DD + d];
    #pragma unroll
    for (int kk = 0; kk < 8; kk++) acc[kk] += wsm[(size_t)(k0 + kk)*DD + j] * wv;
  }
  #pragma unroll
  for (int kk = 0; kk < 8; kk++) WT[(size_t)d*DSS + k0 + kk] = __float2bfloat16(acc[kk]);
}

// fp32 -> bf16 copy (n multiple of 1024)
__global__ __launch_bounds__(256) void conv_bf16(
    const float* __restrict__ src, bf16* __restrict__ dst)
{
  int i = (blockIdx.x*256 + threadIdx.x)*4;
  float4 v = *(const float4*)(src + i);
  bf16 t[4] = {__float2bfloat16(v.x), __float2bfloat16(v.y),
               __float2bfloat16(v.z), __float2bfloat16(v.w)};
  *(uint2*)(dst + i) = *(uint2*)t;
}

// paired transpose: z=0 -> (s0,d0), z=1 -> (s1,d1); dst[c][r] = bf16(src[r][c])
__global__ __launch_bounds__(256) void transpose_pair(
    const float* __restrict__ s0, bf16* __restrict__ d0,
    const float* __restrict__ s1, bf16* __restrict__ d1, int R, int C)
{
  const float* src = blockIdx.z ? s1 : s0;
  bf16* dst = blockIdx.z ? d1 : d0;
  __shared__ float t[32][33];
  int c0 = blockIdx.x*32, r0 = blockIdx.y*32;
  int tr = threadIdx.x >> 5, tc = threadIdx.x & 31;
  #pragma unroll
  for (int i = 0; i < 4; i++)
    t[tr + i*8][tc] = src[(size_t)(r0 + tr + i*8)*C + c0 + tc];
  __syncthreads();
  #pragma unroll
  for (int i = 0; i < 4; i++)
    dst[(size_t)(c0 + tr + i*8)*R + r0 + tc] = __float2bfloat16(t[tc][tr + i*8]);
}

// ---------------------------------------------------------------------------
// MFMA GEMM: C[M,N] = A[M,K] @ Bt[N,K]^T, bf16 in, fp32 acc, 64x64 tile.
// Optional fused epilogues: bias/rowvec/relu; GAT attention-score partials
// (atomicAdd of per-row tile reductions against atts/attd).
// ---------------------------------------------------------------------------
template<typename TC>
__global__ __launch_bounds__(256) void gemm_mfma(
    const bf16* __restrict__ A, const bf16* __restrict__ Bt, TC* __restrict__ C,
    int M, int N, int K,
    const float* __restrict__ bias, const float* __restrict__ rowvec, int relu,
    const float* __restrict__ atts, const float* __restrict__ attd,
    float* __restrict__ as_out, float* __restrict__ ad_out)
{
  __shared__ __align__(16) bf16 Asl[64*72];
  __shared__ __align__(16) bf16 Bsl[64*72];
  int tid = threadIdx.x;
  int w = tid >> 6, lane = tid & 63;
  int q = lane >> 4, mn = lane & 15;
  int row0 = blockIdx.y*64, col0 = blockIdx.x*64;
  int sr = tid >> 3, sc = tid & 7;
  floatx4 acc[4];
  #pragma unroll
  for (int t = 0; t < 4; t++) acc[t] = (floatx4){0.f, 0.f, 0.f, 0.f};

  for (int k0 = 0; k0 < K; k0 += 64) {
    uint4 a0 = *(const uint4*)(A  + (size_t)(row0 + sr)*K      + k0 + sc*8);
    uint4 a1 = *(const uint4*)(A  + (size_t)(row0 + 32 + sr)*K + k0 + sc*8);
    uint4 b0 = *(const uint4*)(Bt + (size_t)(col0 + sr)*K      + k0 + sc*8);
    uint4 b1 = *(const uint4*)(Bt + (size_t)(col0 + 32 + sr)*K + k0 + sc*8);
    __syncthreads();
    *(uint4*)&Asl[sr*72 + sc*8]        = a0;
    *(uint4*)&Asl[(sr + 32)*72 + sc*8] = a1;
    *(uint4*)&Bsl[sr*72 + sc*8]        = b0;
    *(uint4*)&Bsl[(sr + 32)*72 + sc*8] = b1;
    __syncthreads();
    #pragma unroll
    for (int kk = 0; kk < 64; kk += 32) {
      short8 af = *(const short8*)&Asl[(w*16 + mn)*72 + kk + q*8];
      #pragma unroll
      for (int t = 0; t < 4; t++) {
        short8 bfr = *(const short8*)&Bsl[(t*16 + mn)*72 + kk + q*8];
        acc[t] = __builtin_amdgcn_mfma_f32_16x16x32_bf16(af, bfr, acc[t], 0, 0, 0);
      }
    }
  }
  // fused GAT attention-score partials (raw acc, pre-bias): this 64-col tile
  // lies within head h = col0>>8; reduce over cols, atomicAdd per row.
  if (as_out) {
    int h = col0 >> 8, cbase = col0 & 255;
    float ps[4] = {}, pd[4] = {};
    #pragma unroll
    for (int t = 0; t < 4; t++) {
      float av = atts[h*DD + cbase + t*16 + mn];
      float dv = attd[h*DD + cbase + t*16 + mn];
      #pragma unroll
      for (int rg = 0; rg < 4; rg++) {
        ps[rg] += acc[t][rg]*av;
        pd[rg] += acc[t][rg]*dv;
      }
    }
    #pragma unroll
    for (int rg = 0; rg < 4; rg++) {
      #pragma unroll
      for (int off = 1; off < 16; off <<= 1) {
        ps[rg] += __shfl_xor(ps[rg], off);
        pd[rg] += __shfl_xor(pd[rg], off);
      }
      if (mn == 0) {
        int r = row0 + w*16 + q*4 + rg;
        atomicAdd(&as_out[r*4 + h], ps[rg]);
        atomicAdd(&ad_out[r*4 + h], pd[rg]);
      }
    }
  }
  #pragma unroll
  for (int t = 0; t < 4; t++) {
    #pragma unroll
    for (int rg = 0; rg < 4; rg++) {
      int r = row0 + w*16 + q*4 + rg;
      int c = col0 + t*16 + mn;
      float v = acc[t][rg];
      if (bias)   v += bias[c];
      if (rowvec) v += rowvec[(size_t)(r >> 10)*N + c];
      if (relu)   v = fmaxf(v, 0.f);
      stC(&C[(size_t)r*N + c], v);
    }
  }
}

// ---------------------------------------------------------------------------
// CSR build + misc init (self-loops included: counts start at 1)
// ---------------------------------------------------------------------------
__global__ void csr_init(int* counts, int* fc, float* zz /*a_s1,a_d1,a_s2,a_d2*/,
                         const float* __restrict__ cb1, const float* __restrict__ ab1,
                         float* __restrict__ bias2)
{
  int i = blockIdx.x*256 + threadIdx.x;     // 0..8191
  counts[i] = 1; fc[i] = 0;
  float4 z = make_float4(0.f, 0.f, 0.f, 0.f);
  #pragma unroll
  for (int j = 0; j < 4; j++) ((float4*)zz)[i*4 + j] = z;  // 8192*16 floats
  if (i < 256) bias2[i] = cb1[i];
  else if (i < 512) bias2[i] = ab1[i - 256];
}
__global__ void csr_count(const int* __restrict__ ei, int* __restrict__ counts) {
  int e = blockIdx.x*256 + threadIdx.x;
  if (e < NE) atomicAdd(&counts[ei[NE + e]], 1);
}
__global__ __launch_bounds__(1024) void scan_kernel(
    const int* __restrict__ counts, int* __restrict__ offs)
{
  __shared__ int part[1024];
  int t = threadIdx.x;
  int local[8]; int sum = 0;
  #pragma unroll
  for (int i = 0; i < 8; i++) { local[i] = sum; sum += counts[t*8 + i]; }
  part[t] = sum;
  __syncthreads();
  for (int off = 1; off < 1024; off <<= 1) {
    int v = (t >= off) ? part[t - off] : 0;
    __syncthreads();
    part[t] += v;
    __syncthreads();
  }
  int base = (t == 0) ? 0 : part[t - 1];
  #pragma unroll
  for (int i = 0; i < 8; i++) offs[t*8 + i] = base + local[i];
  if (t == 1023) offs[BN] = part[1023];
}
__global__ void csr_fill(const int* __restrict__ ei, const int* __restrict__ offs,
                         int* __restrict__ fc, int* __restrict__ csr)
{
  int idx = blockIdx.x*256 + threadIdx.x;
  if (idx < NE) {
    int sn = ei[idx], dn = ei[NE + idx];
    int p = offs[dn] + atomicAdd(&fc[dn], 1);
    csr[p] = sn;
  } else if (idx < NEP) {
    int i2 = idx - NE;
    int p = offs[i2] + atomicAdd(&fc[i2], 1);
    csr[p] = i2;
  }
}

// ---------------------------------------------------------------------------
// GAT aggregation v2: block per dst node, wave per head. Lane-parallel scoring
// pass caches csr + softmax weights in LDS (cap DEGCAP, cold-path fallback);
// aggregation pass: 2 broadcast ds_reads + 1 gather + 4 fma per edge.
// 1/den folded into epilogue. Head-mean + bias + relu (+edit); bf16 out.
// ---------------------------------------------------------------------------
__global__ __launch_bounds__(256) void gat_aggregate(
    const bf16* __restrict__ xw, const float* __restrict__ a_s, const float* __restrict__ a_d,
    const int* __restrict__ offs, const int* __restrict__ csr,
    const float* __restrict__ bias, const float* __restrict__ editadd,
    bf16* __restrict__ xout)
{
  int i = blockIdx.x, t = threadIdx.x;
  int h = t >> 6, l = t & 63;
  int beg = offs[i], end = offs[i + 1], deg = end - beg;
  __shared__ float sacc[HD];
  __shared__ float sal[4][DEGCAP];
  __shared__ int   scsr[DEGCAP];
  float adh = a_d[i*4 + h];
  // scoring pass (lane-parallel): al -> LDS, running max
  float mloc = -1e30f;
  for (int idx = l; idx < deg; idx += 64) {
    int sn = csr[beg + idx];
    if (h == 0 && idx < DEGCAP) scsr[idx] = sn;
    float al = a_s[sn*4 + h] + adh;
    al = al > 0.f ? al : 0.2f*al;
    if (idx < DEGCAP) sal[h][idx] = al;
    mloc = fmaxf(mloc, al);
  }
  float mh = wredmax(mloc);                     // finite: deg >= 1
  float sloc = 0.f;
  for (int idx = l; idx < deg; idx += 64) {
    float al;
    if (idx < DEGCAP) al = sal[h][idx];
    else {
      int sn = csr[beg + idx];
      al = a_s[sn*4 + h] + adh;
      al = al > 0.f ? al : 0.2f*al;
    }
    float wv = expf(al - mh);
    if (idx < DEGCAP) sal[h][idx] = wv;
    sloc += wv;
  }
  float inv = 1.f / wredsum(sloc);              // denom >= 1
  __syncthreads();
  // aggregation pass: lane l covers channels l*4..l*4+3 of head h
  const bf16* xbase = xw + h*DD + l*4;
  float acc0 = 0.f, acc1 = 0.f, acc2 = 0.f, acc3 = 0.f;
  int cached = deg < DEGCAP ? deg : DEGCAP;
  for (int idx = 0; idx < cached; idx++) {
    int sn = scsr[idx];
    float wv = sal[h][idx];
    uint2 u = *(const uint2*)(xbase + (size_t)sn*HD);
    acc0 += wv*bf_lo(u.x); acc1 += wv*bf_hi(u.x);
    acc2 += wv*bf_lo(u.y); acc3 += wv*bf_hi(u.y);
  }
  for (int idx = cached; idx < deg; idx++) {    // cold path (deg > DEGCAP)
    int sn = csr[beg + idx];
    float al = a_s[sn*4 + h] + adh;
    al = al > 0.f ? al : 0.2f*al;
    float wv = expf(al - mh);
    uint2 u = *(const uint2*)(xbase + (size_t)sn*HD);
    acc0 += wv*bf_lo(u.x); acc1 += wv*bf_hi(u.x);
    acc2 += wv*bf_lo(u.y); acc3 += wv*bf_hi(u.y);
  }
  sacc[h*DD + l*4 + 0] = acc0*inv;
  sacc[h*DD + l*4 + 1] = acc1*inv;
  sacc[h*DD + l*4 + 2] = acc2*inv;
  sacc[h*DD + l*4 + 3] = acc3*inv;
  __syncthreads();
  if (t < 64) {
    int b = i >> 10;
    #pragma unroll
    for (int j = 0; j < 4; j++) {
      int d = t*4 + j;
      float v = 0.25f*(sacc[d] + sacc[DD + d] + sacc[2*DD + d] + sacc[3*DD + d]) + bias[d];
      v = fmaxf(v, 0.f);
      if (editadd) v += editadd[b*DD + d];
      xout[(size_t)i*DD + d] = __float2bfloat16(v);
    }
  }
}

// comb = node2 + softmax2(node2.textf, node2.editp)@[textf;editp] + mhavec
__global__ __launch_bounds__(64) void comb_kernel(
    bf16* __restrict__ nodeb, const float* __restrict__ textf,
    const float* __restrict__ editp, const float* __restrict__ mhavec)
{
  int r = blockIdx.x, b = r >> 10, l = threadIdx.x;
  float n4[4], t4[4], e4[4];
  float s0 = 0.f, s1 = 0.f;
  #pragma unroll
  for (int i = 0; i < 4; i++) {
    int d = l + 64*i;
    float nv = toF(nodeb[(size_t)r*DD + d]);
    float tv = textf[b*DD + d];
    float ev = editp[b*DD + d];
    n4[i] = nv; t4[i] = tv; e4[i] = ev;
    s0 += nv*tv; s1 += nv*ev;
  }
  s0 = wredsum(s0); s1 = wredsum(s1);
  float mm = fmaxf(s0, s1);
  float e0 = expf(s0 - mm), e1 = expf(s1 - mm);
  float inv = 1.f / (e0 + e1);
  float p0 = e0*inv, p1 = e1*inv;
  #pragma unroll
  for (int i = 0; i < 4; i++) {
    int d = l + 64*i;
    nodeb[(size_t)r*DD + d] = __float2bfloat16(n4[i] + p0*t4[i] + p1*e4[i] + mhavec[b*DD + d]);
  }
}

// final heads from combined h1 [8192][512] (cols 0..255 coords-hidden, 256..511 aa-hidden)
__global__ __launch_bounds__(64) void finals_kernel(
    const float* __restrict__ h1,
    const float* __restrict__ cw2, const float* __restrict__ cb2,
    const float* __restrict__ aw2, const float* __restrict__ ab2,
    float* __restrict__ out)
{
  int r = blockIdx.x, l = threadIdx.x;
  float c4[4], a4[4];
  #pragma unroll
  for (int i = 0; i < 4; i++) {
    c4[i] = h1[(size_t)r*512 + l + 64*i];
    a4[i] = h1[(size_t)r*512 + 256 + l + 64*i];
  }
  #pragma unroll
  for (int j = 0; j < 3; j++) {
    float p = 0.f;
    #pragma unroll
    for (int i = 0; i < 4; i++) p += c4[i] * cw2[(size_t)(l + 64*i)*3 + j];
    p = wredsum(p);
    if (l == 0) out[(size_t)r*3 + j] = p + cb2[j];
  }
  __shared__ float lg[20];
  for (int j = 0; j < 20; j++) {
    float p = 0.f;
    #pragma unroll
    for (int i = 0; i < 4; i++) p += a4[i] * aw2[(size_t)(l + 64*i)*20 + j];
    p = wredsum(p);
    if (l == 0) lg[j] = p + ab2[j];
  }
  __syncthreads();
  if (l < 20) {
    float mm = -1e30f;
    for (int j = 0; j < 20; j++) mm = fmaxf(mm, lg[j]);
    float den = 0.f;
    for (int j = 0; j < 20; j++) den += expf(lg[j] - mm);
    out[24576 + (size_t)r*20 + l] = expf(lg[l] - mm) / den;
  }
}

// ---------------------------------------------------------------------------
extern "C" void kernel_launch(void* const* d_in, const int* in_sizes, int n_in,
                              void* d_out, int out_size, void* d_ws, size_t ws_size,
                              hipStream_t stream)
{
  (void)in_sizes; (void)n_in; (void)out_size; (void)ws_size;
  const float* structure_emb = (const float*)d_in[0];
  const float* text_emb      = (const float*)d_in[1];
  const float* edit_emb      = (const float*)d_in[3];
  const float* ws_w    = (const float*)d_in[4];
  const float* bs_b    = (const float*)d_in[5];
  const float* wt_w    = (const float*)d_in[6];
  const float* bt_b    = (const float*)d_in[7];
  const float* we_w    = (const float*)d_in[8];
  const float* be_b    = (const float*)d_in[9];
  const float* wp_w    = (const float*)d_in[10];
  const float* bp_b    = (const float*)d_in[11];
  const float* g1_lin  = (const float*)d_in[12];
  const float* g1_as   = (const float*)d_in[13];
  const float* g1_ad   = (const float*)d_in[14];
  const float* g1_b    = (const float*)d_in[15];
  const float* g2_lin  = (const float*)d_in[16];
  const float* g2_as   = (const float*)d_in[17];
  const float* g2_ad   = (const float*)d_in[18];
  const float* g2_b    = (const float*)d_in[19];
  const float* mha_iw  = (const float*)d_in[20];
  const float* mha_ib  = (const float*)d_in[21];
  const float* mha_ow  = (const float*)d_in[22];
  const float* mha_ob  = (const float*)d_in[23];
  const float* cw1     = (const float*)d_in[24];
  const float* cb1     = (const float*)d_in[25];
  const float* cw2     = (const float*)d_in[26];
  const float* cb2     = (const float*)d_in[27];
  const float* aw1     = (const float*)d_in[28];
  const float* ab1     = (const float*)d_in[29];
  const float* aw2     = (const float*)d_in[30];
  const float* ab2     = (const float*)d_in[31];
  const int*  edge_index = (const int*)d_in[32];
  float* out = (float*)d_out;

  // --- workspace layout (~24 MB) ---
  char* p = (char*)d_ws;
  // 16 MB big region, time-multiplexed: sembB (12.6MB) -> xwb (16MB) -> h1 (16MB)
  bf16*  sembB = (bf16*)p;
  bf16*  xwb   = (bf16*)p;
  float* h1    = (float*)p;              // [8192][512]
  p += 16777216;
  bf16* bufB = (bf16*)p; p += 4194304;   // [8192][256] bf16: x0 -> x1e -> node2 -> comb
  bf16* g1T  = (bf16*)p; p += 524288;    // [1024][256]
  bf16* g2T  = (bf16*)p; p += 524288;
  bf16* W2T  = (bf16*)p; p += 262144;    // [512][256]: cw1T ++ aw1T
  bf16* WfT  = (bf16*)p; p += 393216;    // [256][768]
  float* textf  = (float*)p; p += 8192;
  float* editp  = (float*)p; p += 8192;
  float* vhws   = (float*)p; p += 8192;
  float* mhavec = (float*)p; p += 8192;
  float* cvec   = (float*)p; p += 8192;
  float* bias2  = (float*)p; p += 2048;
  float* a_s1   = (float*)p; p += 131072;  // zz block: a_s1,a_d1,a_s2,a_d2 contiguous
  float* a_d1   = (float*)p; p += 131072;
  float* a_s2   = (float*)p; p += 131072;
  float* a_d2   = (float*)p; p += 131072;
  int* counts = (int*)p; p += 32768;
  int* offs   = (int*)p; p += 32784;
  int* fc     = (int*)p; p += 32768;
  int* csr    = (int*)p; p += NEP*4;

  // per-batch vectors + weight prep
  pk_textedit<<<dim3(BB,4), 256, 0, stream>>>(text_emb, edit_emb, wt_w, bt_b, we_w, be_b, textf, editp);
  wfullT_kernel<<<96, 256, 0, stream>>>(ws_w, wp_w, WfT);
  pk_vh<<<dim3(BB,64), 256, 0, stream>>>(textf, mha_iw, mha_ib, vhws);
  pk_mhavec<<<dim3(BB,64), 256, 0, stream>>>(vhws, mha_ow, mha_ob, mhavec);
  pk_cvec<<<dim3(BB,4), 256, 0, stream>>>(textf, editp, bs_b, wp_w, bp_b, cvec);
  conv_bf16<<<(BN*DSS)/1024, 256, 0, stream>>>(structure_emb, sembB);
  transpose_pair<<<dim3(32,8,2), 256, 0, stream>>>(g1_lin, g1T, g2_lin, g2T, DD, HD);
  transpose_pair<<<dim3(8,8,2),  256, 0, stream>>>(cw1, W2T, aw1, W2T + 65536, DD, DD);

  // CSR build + zero score accumulators + concat head bias
  csr_init<<<BN/256, 256, 0, stream>>>(counts, fc, a_s1, cb1, ab1, bias2);
  csr_count<<<NE/256, 256, 0, stream>>>(edge_index, counts);
  scan_kernel<<<1, 1024, 0, stream>>>(counts, offs);
  csr_fill<<<(NEP + 255)/256, 256, 0, stream>>>(edge_index, offs, fc, csr);

  // x0 = semb @ Wfull + cvec[batch]  -> bufB (bf16)
  gemm_mfma<bf16><<<dim3(DD/64, BN/64), 256, 0, stream>>>(
      sembB, WfT, bufB, BN, DD, DSS, nullptr, cvec, 0,
      nullptr, nullptr, nullptr, nullptr);

  // GAT layer 1 (xw gemm + fused attention scores)
  gemm_mfma<bf16><<<dim3(HD/64, BN/64), 256, 0, stream>>>(
      bufB, g1T, xwb, BN, HD, DD, nullptr, nullptr, 0,
      g1_as, g1_ad, a_s1, a_d1);
  gat_aggregate<<<BN, 256, 0, stream>>>(xwb, a_s1, a_d1, offs, csr, g1_b, editp, bufB);

  // GAT layer 2
  gemm_mfma<bf16><<<dim3(HD/64, BN/64), 256, 0, stream>>>(
      bufB, g2T, xwb, BN, HD, DD, nullptr, nullptr, 0,
      g2_as, g2_ad, a_s2, a_d2);
  gat_aggregate<<<BN, 256, 0, stream>>>(xwb, a_s2, a_d2, offs, csr, g2_b, nullptr, bufB);

  // comb (in place on bufB)
  comb_kernel<<<BN, 64, 0, stream>>>(bufB, textf, editp, mhavec);

  // combined head gemm: [comb]@[cw1T;aw1T]^T + [cb1;ab1], relu -> h1 [8192][512]
  gemm_mfma<float><<<dim3(512/64, BN/64), 256, 0, stream>>>(
      bufB, W2T, h1, BN, 512, DD, bias2, nullptr, 1,
      nullptr, nullptr, nullptr, nullptr);
  finals_kernel<<<BN, 64, 0, stream>>>(h1, cw2, cb2, aw2, ab2, out);
}

// Round 6
// 379.805 us; speedup vs baseline: 1.6366x; 1.0775x over previous
//
#include <hip/hip_runtime.h>
#include <hip/hip_bf16.h>

// Problem constants
#define BB 8
#define NN 1024
#define BN 8192       // B*N
#define DD 256
#define HEADS 4
#define HD 1024       // HEADS*D
#define DSS 768
#define DTT 128
#define NE 131072     // raw edges
#define NEP (NE + BN) // + self loops
#define DEGCAP 256    // LDS-cached edges per node (max in-degree ~40 for this input)

typedef __hip_bfloat16 bf16;
typedef __attribute__((ext_vector_type(8))) short short8;   // 8 bf16 (4 VGPRs)
typedef __attribute__((ext_vector_type(4))) float floatx4;  // MFMA C/D

__device__ __forceinline__ float toF(bf16 x){ return __bfloat162float(x); }
__device__ __forceinline__ void stC(float* p, float v){ *p = v; }
__device__ __forceinline__ void stC(bf16* p, float v){ *p = __float2bfloat16(v); }
__device__ __forceinline__ float bf_lo(unsigned u){ return __uint_as_float(u << 16); }
__device__ __forceinline__ float bf_hi(unsigned u){ return __uint_as_float(u & 0xffff0000u); }

__device__ __forceinline__ float wredsum(float v){
  #pragma unroll
  for (int off = 32; off; off >>= 1) v += __shfl_xor(v, off);
  return v;
}
__device__ __forceinline__ float wredmax(float v){
  #pragma unroll
  for (int off = 32; off; off >>= 1) v = fmaxf(v, __shfl_xor(v, off));
  return v;
}

// ---------------------------------------------------------------------------
// Per-batch small vectors (parallelized)
// ---------------------------------------------------------------------------
__global__ __launch_bounds__(256) void pk_textedit(
    const float* __restrict__ text_emb, const float* __restrict__ edit_emb,
    const float* __restrict__ wt, const float* __restrict__ bt,
    const float* __restrict__ we, const float* __restrict__ be,
    float* __restrict__ textf, float* __restrict__ editp)
{
  int b = blockIdx.x, l = threadIdx.x & 63, qq = threadIdx.x >> 6;
  int d = blockIdx.y*64 + l;
  __shared__ float red[2][4][64];
  float tf = 0.f;
  for (int k = qq*32; k < qq*32 + 32; k++) tf += text_emb[b*DTT + k] * wt[(size_t)k*DD + d];
  float ep = 0.f;
  for (int k = qq*192; k < qq*192 + 192; k++) ep += edit_emb[b*DSS + k] * we[(size_t)k*DD + d];
  red[0][qq][l] = tf; red[1][qq][l] = ep;
  __syncthreads();
  if (threadIdx.x < 64) {
    int dd = blockIdx.y*64 + threadIdx.x;
    textf[b*DD + dd] = red[0][0][threadIdx.x]+red[0][1][threadIdx.x]+red[0][2][threadIdx.x]+red[0][3][threadIdx.x] + bt[dd];
    editp[b*DD + dd] = red[1][0][threadIdx.x]+red[1][1][threadIdx.x]+red[1][2][threadIdx.x]+red[1][3][threadIdx.x] + be[dd];
  }
}

// vh[b,d] = mha_ib[512+d] + textf[b]@mha_iw[512+d,:]   (grid (8,64), wave/dot)
__global__ __launch_bounds__(256) void pk_vh(
    const float* __restrict__ textf, const float* __restrict__ mha_iw,
    const float* __restrict__ mha_ib, float* __restrict__ vh)
{
  int b = blockIdx.x, w = threadIdx.x >> 6, l = threadIdx.x & 63;
  int d = blockIdx.y*4 + w;
  float p = 0.f;
  #pragma unroll
  for (int i = 0; i < 4; i++) p += textf[b*DD + l + 64*i] * mha_iw[(size_t)(512 + d)*DD + l + 64*i];
  p = wredsum(p);
  if (l == 0) vh[b*DD + d] = p + mha_ib[512 + d];
}

// mhavec[b,d] = mha_ob[d] + vh[b]@mha_ow[d,:]   (exact collapsed MHA)
__global__ __launch_bounds__(256) void pk_mhavec(
    const float* __restrict__ vh, const float* __restrict__ mha_ow,
    const float* __restrict__ mha_ob, float* __restrict__ mhavec)
{
  int b = blockIdx.x, w = threadIdx.x >> 6, l = threadIdx.x & 63;
  int d = blockIdx.y*4 + w;
  float p = 0.f;
  #pragma unroll
  for (int i = 0; i < 4; i++) p += vh[b*DD + l + 64*i] * mha_ow[(size_t)d*DD + l + 64*i];
  p = wredsum(p);
  if (l == 0) mhavec[b*DD + d] = p + mha_ob[d];
}

// cvec = bs@wp0 + textf@wp1 + editp@wp2 + bp + editp   (grid (8,4))
__global__ __launch_bounds__(256) void pk_cvec(
    const float* __restrict__ textf, const float* __restrict__ editp,
    const float* __restrict__ bs, const float* __restrict__ wp, const float* __restrict__ bp,
    float* __restrict__ cvec)
{
  int b = blockIdx.x, l = threadIdx.x & 63, qq = threadIdx.x >> 6;
  int d = blockIdx.y*64 + l;
  __shared__ float red[4][64];
  float cv = 0.f;
  for (int k = qq*64; k < qq*64 + 64; k++) cv += bs[k] * wp[(size_t)k*DD + d];
  for (int k = qq*64; k < qq*64 + 64; k++) cv += textf[b*DD + k] * wp[(size_t)(DD + k)*DD + d];
  for (int k = qq*64; k < qq*64 + 64; k++) cv += editp[b*DD + k] * wp[(size_t)(2*DD + k)*DD + d];
  red[qq][l] = cv;
  __syncthreads();
  if (threadIdx.x < 64) {
    int dd = blockIdx.y*64 + threadIdx.x;
    cvec[b*DD + dd] = red[0][threadIdx.x]+red[1][threadIdx.x]+red[2][threadIdx.x]+red[3][threadIdx.x]
                      + bp[dd] + editp[b*DD + dd];
  }
}

// WfullT[d][k] = sum_j ws[k,j]*wp[j,d]  -> bf16 [256][768]  (grid 96)
__global__ __launch_bounds__(256) void wfullT_kernel(
    const float* __restrict__ wsm, const float* __restrict__ wp, bf16* __restrict__ WT)
{
  int k0 = blockIdx.x*8, d = threadIdx.x;
  float acc[8] = {};
  for (int j = 0; j < DD; j++) {
    float wv = wp[(size_t)j*DD + d];
    #pragma unroll
    for (int kk = 0; kk < 8; kk++) acc[kk] += wsm[(size_t)(k0 + kk)*DD + j] * wv;
  }
  #pragma unroll
  for (int kk = 0; kk < 8; kk++) WT[(size_t)d*DSS + k0 + kk] = __float2bfloat16(acc[kk]);
}

// fp32 -> bf16 copy (n multiple of 1024)
__global__ __launch_bounds__(256) void conv_bf16(
    const float* __restrict__ src, bf16* __restrict__ dst)
{
  int i = (blockIdx.x*256 + threadIdx.x)*4;
  float4 v = *(const float4*)(src + i);
  bf16 t[4] = {__float2bfloat16(v.x), __float2bfloat16(v.y),
               __float2bfloat16(v.z), __float2bfloat16(v.w)};
  *(uint2*)(dst + i) = *(uint2*)t;
}

// paired transpose: z=0 -> (s0,d0), z=1 -> (s1,d1); dst[c][r] = bf16(src[r][c])
__global__ __launch_bounds__(256) void transpose_pair(
    const float* __restrict__ s0, bf16* __restrict__ d0,
    const float* __restrict__ s1, bf16* __restrict__ d1, int R, int C)
{
  const float* src = blockIdx.z ? s1 : s0;
  bf16* dst = blockIdx.z ? d1 : d0;
  __shared__ float t[32][33];
  int c0 = blockIdx.x*32, r0 = blockIdx.y*32;
  int tr = threadIdx.x >> 5, tc = threadIdx.x & 31;
  #pragma unroll
  for (int i = 0; i < 4; i++)
    t[tr + i*8][tc] = src[(size_t)(r0 + tr + i*8)*C + c0 + tc];
  __syncthreads();
  #pragma unroll
  for (int i = 0; i < 4; i++)
    dst[(size_t)(c0 + tr + i*8)*R + r0 + tc] = __float2bfloat16(t[tc][tr + i*8]);
}

// block-diagonal final-head weight: WdT[n][k], n<3: cw2[k][n] (k<256);
// 3<=n<23: aw2[k-256][n-3] (k>=256); else 0.  Plus bias23[n].
__global__ __launch_bounds__(256) void wd_build(
    const float* __restrict__ cw2, const float* __restrict__ cb2,
    const float* __restrict__ aw2, const float* __restrict__ ab2,
    bf16* __restrict__ WdT, float* __restrict__ bias23)
{
  int idx = blockIdx.x*256 + threadIdx.x;     // 0..32767
  int n = idx >> 9, k = idx & 511;
  float v = 0.f;
  if (n < 3) { if (k < 256) v = cw2[(size_t)k*3 + n]; }
  else if (n < 23) { if (k >= 256) v = aw2[(size_t)(k - 256)*20 + (n - 3)]; }
  WdT[idx] = __float2bfloat16(v);
  if (idx < 64) bias23[idx] = idx < 3 ? cb2[idx] : (idx < 23 ? ab2[idx - 3] : 0.f);
}

// ---------------------------------------------------------------------------
// MFMA GEMM: C[M,N] = A[M,K] @ Bt[N,K]^T, bf16 in, fp32 acc, 64x64 tile.
// Optional fused epilogues: bias/rowvec/relu; GAT attention-score partials.
// ---------------------------------------------------------------------------
template<typename TC>
__global__ __launch_bounds__(256) void gemm_mfma(
    const bf16* __restrict__ A, const bf16* __restrict__ Bt, TC* __restrict__ C,
    int M, int N, int K,
    const float* __restrict__ bias, const float* __restrict__ rowvec, int relu,
    const float* __restrict__ atts, const float* __restrict__ attd,
    float* __restrict__ as_out, float* __restrict__ ad_out)
{
  __shared__ __align__(16) bf16 Asl[64*72];
  __shared__ __align__(16) bf16 Bsl[64*72];
  int tid = threadIdx.x;
  int w = tid >> 6, lane = tid & 63;
  int q = lane >> 4, mn = lane & 15;
  int row0 = blockIdx.y*64, col0 = blockIdx.x*64;
  int sr = tid >> 3, sc = tid & 7;
  floatx4 acc[4];
  #pragma unroll
  for (int t = 0; t < 4; t++) acc[t] = (floatx4){0.f, 0.f, 0.f, 0.f};

  for (int k0 = 0; k0 < K; k0 += 64) {
    uint4 a0 = *(const uint4*)(A  + (size_t)(row0 + sr)*K      + k0 + sc*8);
    uint4 a1 = *(const uint4*)(A  + (size_t)(row0 + 32 + sr)*K + k0 + sc*8);
    uint4 b0 = *(const uint4*)(Bt + (size_t)(col0 + sr)*K      + k0 + sc*8);
    uint4 b1 = *(const uint4*)(Bt + (size_t)(col0 + 32 + sr)*K + k0 + sc*8);
    __syncthreads();
    *(uint4*)&Asl[sr*72 + sc*8]        = a0;
    *(uint4*)&Asl[(sr + 32)*72 + sc*8] = a1;
    *(uint4*)&Bsl[sr*72 + sc*8]        = b0;
    *(uint4*)&Bsl[(sr + 32)*72 + sc*8] = b1;
    __syncthreads();
    #pragma unroll
    for (int kk = 0; kk < 64; kk += 32) {
      short8 af = *(const short8*)&Asl[(w*16 + mn)*72 + kk + q*8];
      #pragma unroll
      for (int t = 0; t < 4; t++) {
        short8 bfr = *(const short8*)&Bsl[(t*16 + mn)*72 + kk + q*8];
        acc[t] = __builtin_amdgcn_mfma_f32_16x16x32_bf16(af, bfr, acc[t], 0, 0, 0);
      }
    }
  }
  if (as_out) {   // fused GAT attention-score partials (head h = col0>>8)
    int h = col0 >> 8, cbase = col0 & 255;
    float ps[4] = {}, pd[4] = {};
    #pragma unroll
    for (int t = 0; t < 4; t++) {
      float av = atts[h*DD + cbase + t*16 + mn];
      float dv = attd[h*DD + cbase + t*16 + mn];
      #pragma unroll
      for (int rg = 0; rg < 4; rg++) {
        ps[rg] += acc[t][rg]*av;
        pd[rg] += acc[t][rg]*dv;
      }
    }
    #pragma unroll
    for (int rg = 0; rg < 4; rg++) {
      #pragma unroll
      for (int off = 1; off < 16; off <<= 1) {
        ps[rg] += __shfl_xor(ps[rg], off);
        pd[rg] += __shfl_xor(pd[rg], off);
      }
      if (mn == 0) {
        int r = row0 + w*16 + q*4 + rg;
        atomicAdd(&as_out[r*4 + h], ps[rg]);
        atomicAdd(&ad_out[r*4 + h], pd[rg]);
      }
    }
  }
  #pragma unroll
  for (int t = 0; t < 4; t++) {
    #pragma unroll
    for (int rg = 0; rg < 4; rg++) {
      int r = row0 + w*16 + q*4 + rg;
      int c = col0 + t*16 + mn;
      float v = acc[t][rg];
      if (bias)   v += bias[c];
      if (rowvec) v += rowvec[(size_t)(r >> 10)*N + c];
      if (relu)   v = fmaxf(v, 0.f);
      stC(&C[(size_t)r*N + c], v);
    }
  }
}

// ---------------------------------------------------------------------------
// CSR build + misc init (self-loops included: counts start at 1)
// ---------------------------------------------------------------------------
__global__ void csr_init(int* counts, int* fc, float* zz /*a_s1,a_d1,a_s2,a_d2*/,
                         const float* __restrict__ cb1, const float* __restrict__ ab1,
                         float* __restrict__ bias2)
{
  int i = blockIdx.x*256 + threadIdx.x;     // 0..8191
  counts[i] = 1; fc[i] = 0;
  float4 z = make_float4(0.f, 0.f, 0.f, 0.f);
  #pragma unroll
  for (int j = 0; j < 4; j++) ((float4*)zz)[i*4 + j] = z;
  if (i < 256) bias2[i] = cb1[i];
  else if (i < 512) bias2[i] = ab1[i - 256];
}
__global__ void csr_count(const int* __restrict__ ei, int* __restrict__ counts) {
  int e = blockIdx.x*256 + threadIdx.x;
  if (e < NE) atomicAdd(&counts[ei[NE + e]], 1);
}
__global__ __launch_bounds__(1024) void scan_kernel(
    const int* __restrict__ counts, int* __restrict__ offs)
{
  __shared__ int part[1024];
  int t = threadIdx.x;
  int local[8]; int sum = 0;
  #pragma unroll
  for (int i = 0; i < 8; i++) { local[i] = sum; sum += counts[t*8 + i]; }
  part[t] = sum;
  __syncthreads();
  for (int off = 1; off < 1024; off <<= 1) {
    int v = (t >= off) ? part[t - off] : 0;
    __syncthreads();
    part[t] += v;
    __syncthreads();
  }
  int base = (t == 0) ? 0 : part[t - 1];
  #pragma unroll
  for (int i = 0; i < 8; i++) offs[t*8 + i] = base + local[i];
  if (t == 1023) offs[BN] = part[1023];
}
__global__ void csr_fill(const int* __restrict__ ei, const int* __restrict__ offs,
                         int* __restrict__ fc, int* __restrict__ csr)
{
  int idx = blockIdx.x*256 + threadIdx.x;
  if (idx < NE) {
    int sn = ei[idx], dn = ei[NE + idx];
    int p = offs[dn] + atomicAdd(&fc[dn], 1);
    csr[p] = sn;
  } else if (idx < NEP) {
    int i2 = idx - NE;
    int p = offs[i2] + atomicAdd(&fc[i2], 1);
    csr[p] = i2;
  }
}

// ---------------------------------------------------------------------------
// GAT aggregation v2: block per dst node, wave per head; LDS-cached edge list
// and softmax weights; 1/den folded into epilogue; bf16 out.
// ---------------------------------------------------------------------------
__global__ __launch_bounds__(256) void gat_aggregate(
    const bf16* __restrict__ xw, const float* __restrict__ a_s, const float* __restrict__ a_d,
    const int* __restrict__ offs, const int* __restrict__ csr,
    const float* __restrict__ bias, const float* __restrict__ editadd,
    bf16* __restrict__ xout)
{
  int i = blockIdx.x, t = threadIdx.x;
  int h = t >> 6, l = t & 63;
  int beg = offs[i], end = offs[i + 1], deg = end - beg;
  __shared__ float sacc[HD];
  __shared__ float sal[4][DEGCAP];
  __shared__ int   scsr[DEGCAP];
  float adh = a_d[i*4 + h];
  float mloc = -1e30f;
  for (int idx = l; idx < deg; idx += 64) {
    int sn = csr[beg + idx];
    if (h == 0 && idx < DEGCAP) scsr[idx] = sn;
    float al = a_s[sn*4 + h] + adh;
    al = al > 0.f ? al : 0.2f*al;
    if (idx < DEGCAP) sal[h][idx] = al;
    mloc = fmaxf(mloc, al);
  }
  float mh = wredmax(mloc);                     // finite: deg >= 1
  float sloc = 0.f;
  for (int idx = l; idx < deg; idx += 64) {
    float al;
    if (idx < DEGCAP) al = sal[h][idx];
    else {
      int sn = csr[beg + idx];
      al = a_s[sn*4 + h] + adh;
      al = al > 0.f ? al : 0.2f*al;
    }
    float wv = expf(al - mh);
    if (idx < DEGCAP) sal[h][idx] = wv;
    sloc += wv;
  }
  float inv = 1.f / wredsum(sloc);              // denom >= 1
  __syncthreads();
  const bf16* xbase = xw + h*DD + l*4;
  float acc0 = 0.f, acc1 = 0.f, acc2 = 0.f, acc3 = 0.f;
  int cached = deg < DEGCAP ? deg : DEGCAP;
  for (int idx = 0; idx < cached; idx++) {
    int sn = scsr[idx];
    float wv = sal[h][idx];
    uint2 u = *(const uint2*)(xbase + (size_t)sn*HD);
    acc0 += wv*bf_lo(u.x); acc1 += wv*bf_hi(u.x);
    acc2 += wv*bf_lo(u.y); acc3 += wv*bf_hi(u.y);
  }
  for (int idx = cached; idx < deg; idx++) {    // cold path (deg > DEGCAP)
    int sn = csr[beg + idx];
    float al = a_s[sn*4 + h] + adh;
    al = al > 0.f ? al : 0.2f*al;
    float wv = expf(al - mh);
    uint2 u = *(const uint2*)(xbase + (size_t)sn*HD);
    acc0 += wv*bf_lo(u.x); acc1 += wv*bf_hi(u.x);
    acc2 += wv*bf_lo(u.y); acc3 += wv*bf_hi(u.y);
  }
  sacc[h*DD + l*4 + 0] = acc0*inv;
  sacc[h*DD + l*4 + 1] = acc1*inv;
  sacc[h*DD + l*4 + 2] = acc2*inv;
  sacc[h*DD + l*4 + 3] = acc3*inv;
  __syncthreads();
  if (t < 64) {
    int b = i >> 10;
    #pragma unroll
    for (int j = 0; j < 4; j++) {
      int d = t*4 + j;
      float v = 0.25f*(sacc[d] + sacc[DD + d] + sacc[2*DD + d] + sacc[3*DD + d]) + bias[d];
      v = fmaxf(v, 0.f);
      if (editadd) v += editadd[b*DD + d];
      xout[(size_t)i*DD + d] = __float2bfloat16(v);
    }
  }
}

// comb = node2 + softmax2(node2.textf, node2.editp)@[textf;editp] + mhavec
__global__ __launch_bounds__(64) void comb_kernel(
    bf16* __restrict__ nodeb, const float* __restrict__ textf,
    const float* __restrict__ editp, const float* __restrict__ mhavec)
{
  int r = blockIdx.x, b = r >> 10, l = threadIdx.x;
  float n4[4], t4[4], e4[4];
  float s0 = 0.f, s1 = 0.f;
  #pragma unroll
  for (int i = 0; i < 4; i++) {
    int d = l + 64*i;
    float nv = toF(nodeb[(size_t)r*DD + d]);
    float tv = textf[b*DD + d];
    float ev = editp[b*DD + d];
    n4[i] = nv; t4[i] = tv; e4[i] = ev;
    s0 += nv*tv; s1 += nv*ev;
  }
  s0 = wredsum(s0); s1 = wredsum(s1);
  float mm = fmaxf(s0, s1);
  float e0 = expf(s0 - mm), e1 = expf(s1 - mm);
  float inv = 1.f / (e0 + e1);
  float p0 = e0*inv, p1 = e1*inv;
  #pragma unroll
  for (int i = 0; i < 4; i++) {
    int d = l + 64*i;
    nodeb[(size_t)r*DD + d] = __float2bfloat16(n4[i] + p0*t4[i] + p1*e4[i] + mhavec[b*DD + d]);
  }
}

// final softmax: wave per row from out23 [8192][64] (coords 0..2, logits 3..22)
__global__ __launch_bounds__(256) void fin_softmax(
    const float* __restrict__ out23, float* __restrict__ out)
{
  int r = blockIdx.x*4 + (threadIdx.x >> 6), l = threadIdx.x & 63;
  float v = (l < 23) ? out23[(size_t)r*64 + l] : 0.f;
  if (l < 3) out[(size_t)r*3 + l] = v;
  float lg = (l >= 3 && l < 23) ? v : -1e30f;
  float mm = wredmax(lg);
  float e = (l >= 3 && l < 23) ? expf(lg - mm) : 0.f;
  float den = wredsum(e);
  if (l >= 3 && l < 23) out[24576 + (size_t)r*20 + (l - 3)] = e/den;
}

// ---------------------------------------------------------------------------
extern "C" void kernel_launch(void* const* d_in, const int* in_sizes, int n_in,
                              void* d_out, int out_size, void* d_ws, size_t ws_size,
                              hipStream_t stream)
{
  (void)in_sizes; (void)n_in; (void)out_size; (void)ws_size;
  const float* structure_emb = (const float*)d_in[0];
  const float* text_emb      = (const float*)d_in[1];
  const float* edit_emb      = (const float*)d_in[3];
  const float* ws_w    = (const float*)d_in[4];
  const float* bs_b    = (const float*)d_in[5];
  const float* wt_w    = (const float*)d_in[6];
  const float* bt_b    = (const float*)d_in[7];
  const float* we_w    = (const float*)d_in[8];
  const float* be_b    = (const float*)d_in[9];
  const float* wp_w    = (const float*)d_in[10];
  const float* bp_b    = (const float*)d_in[11];
  const float* g1_lin  = (const float*)d_in[12];
  const float* g1_as   = (const float*)d_in[13];
  const float* g1_ad   = (const float*)d_in[14];
  const float* g1_b    = (const float*)d_in[15];
  const float* g2_lin  = (const float*)d_in[16];
  const float* g2_as   = (const float*)d_in[17];
  const float* g2_ad   = (const float*)d_in[18];
  const float* g2_b    = (const float*)d_in[19];
  const float* mha_iw  = (const float*)d_in[20];
  const float* mha_ib  = (const float*)d_in[21];
  const float* mha_ow  = (const float*)d_in[22];
  const float* mha_ob  = (const float*)d_in[23];
  const float* cw1     = (const float*)d_in[24];
  const float* cb1     = (const float*)d_in[25];
  const float* cw2     = (const float*)d_in[26];
  const float* cb2     = (const float*)d_in[27];
  const float* aw1     = (const float*)d_in[28];
  const float* ab1     = (const float*)d_in[29];
  const float* aw2     = (const float*)d_in[30];
  const float* ab2     = (const float*)d_in[31];
  const int*  edge_index = (const int*)d_in[32];
  float* out = (float*)d_out;

  // --- workspace layout (~24 MB) ---
  char* p = (char*)d_ws;
  // 16 MB big region, time-multiplexed:
  //   sembB (12.6MB) -> xwb (16MB) -> h1b bf16 [8192][512] (8MB) + out23 (2MB)
  bf16*  sembB = (bf16*)p;
  bf16*  xwb   = (bf16*)p;
  bf16*  h1b   = (bf16*)p;
  float* out23 = (float*)(p + 8388608);
  p += 16777216;
  bf16* bufB = (bf16*)p; p += 4194304;   // [8192][256] bf16: x0 -> x1e -> node2 -> comb
  bf16* g1T  = (bf16*)p; p += 524288;    // [1024][256]
  bf16* g2T  = (bf16*)p; p += 524288;
  bf16* W2T  = (bf16*)p; p += 262144;    // [512][256]: cw1T ++ aw1T
  bf16* WfT  = (bf16*)p; p += 393216;    // [256][768]
  bf16* WdT  = (bf16*)p; p += 65536;     // [64][512] block-diag final weight
  float* textf  = (float*)p; p += 8192;
  float* editp  = (float*)p; p += 8192;
  float* vhws   = (float*)p; p += 8192;
  float* mhavec = (float*)p; p += 8192;
  float* cvec   = (float*)p; p += 8192;
  float* bias2  = (float*)p; p += 2048;
  float* bias23 = (float*)p; p += 256;
  float* a_s1   = (float*)p; p += 131072;  // zz block: a_s1,a_d1,a_s2,a_d2
  float* a_d1   = (float*)p; p += 131072;
  float* a_s2   = (float*)p; p += 131072;
  float* a_d2   = (float*)p; p += 131072;
  int* counts = (int*)p; p += 32768;
  int* offs   = (int*)p; p += 32784;
  int* fc     = (int*)p; p += 32768;
  int* csr    = (int*)p; p += NEP*4;

  // per-batch vectors + weight prep
  pk_textedit<<<dim3(BB,4), 256, 0, stream>>>(text_emb, edit_emb, wt_w, bt_b, we_w, be_b, textf, editp);
  wfullT_kernel<<<96, 256, 0, stream>>>(ws_w, wp_w, WfT);
  pk_vh<<<dim3(BB,64), 256, 0, stream>>>(textf, mha_iw, mha_ib, vhws);
  pk_mhavec<<<dim3(BB,64), 256, 0, stream>>>(vhws, mha_ow, mha_ob, mhavec);
  pk_cvec<<<dim3(BB,4), 256, 0, stream>>>(textf, editp, bs_b, wp_w, bp_b, cvec);
  conv_bf16<<<(BN*DSS)/1024, 256, 0, stream>>>(structure_emb, sembB);
  transpose_pair<<<dim3(32,8,2), 256, 0, stream>>>(g1_lin, g1T, g2_lin, g2T, DD, HD);
  transpose_pair<<<dim3(8,8,2),  256, 0, stream>>>(cw1, W2T, aw1, W2T + 65536, DD, DD);
  wd_build<<<128, 256, 0, stream>>>(cw2, cb2, aw2, ab2, WdT, bias23);

  // CSR build + zero score accumulators + concat head bias
  csr_init<<<BN/256, 256, 0, stream>>>(counts, fc, a_s1, cb1, ab1, bias2);
  csr_count<<<NE/256, 256, 0, stream>>>(edge_index, counts);
  scan_kernel<<<1, 1024, 0, stream>>>(counts, offs);
  csr_fill<<<(NEP + 255)/256, 256, 0, stream>>>(edge_index, offs, fc, csr);

  // x0 = semb @ Wfull + cvec[batch]  -> bufB (bf16)
  gemm_mfma<bf16><<<dim3(DD/64, BN/64), 256, 0, stream>>>(
      sembB, WfT, bufB, BN, DD, DSS, nullptr, cvec, 0,
      nullptr, nullptr, nullptr, nullptr);

  // GAT layer 1 (xw gemm + fused attention scores)
  gemm_mfma<bf16><<<dim3(HD/64, BN/64), 256, 0, stream>>>(
      bufB, g1T, xwb, BN, HD, DD, nullptr, nullptr, 0,
      g1_as, g1_ad, a_s1, a_d1);
  gat_aggregate<<<BN, 256, 0, stream>>>(xwb, a_s1, a_d1, offs, csr, g1_b, editp, bufB);

  // GAT layer 2
  gemm_mfma<bf16><<<dim3(HD/64, BN/64), 256, 0, stream>>>(
      bufB, g2T, xwb, BN, HD, DD, nullptr, nullptr, 0,
      g2_as, g2_ad, a_s2, a_d2);
  gat_aggregate<<<BN, 256, 0, stream>>>(xwb, a_s2, a_d2, offs, csr, g2_b, nullptr, bufB);

  // comb (in place on bufB)
  comb_kernel<<<BN, 64, 0, stream>>>(bufB, textf, editp, mhavec);

  // combined head gemm -> h1b bf16 [8192][512] (xwb dead by now)
  gemm_mfma<bf16><<<dim3(512/64, BN/64), 256, 0, stream>>>(
      bufB, W2T, h1b, BN, 512, DD, bias2, nullptr, 1,
      nullptr, nullptr, nullptr, nullptr);

  // final projection as skinny GEMM: out23 = h1b @ Wd + bias23
  gemm_mfma<float><<<dim3(1, BN/64), 256, 0, stream>>>(
      h1b, WdT, out23, BN, 64, 512, bias23, nullptr, 0,
      nullptr, nullptr, nullptr, nullptr);
  fin_softmax<<<BN/4, 256, 0, stream>>>(out23, out);
}

// Round 7
// 340.498 us; speedup vs baseline: 1.8256x; 1.1154x over previous
//
#include <hip/hip_runtime.h>
#include <hip/hip_bf16.h>

// Problem constants
#define BB 8
#define NN 1024
#define BN 8192       // B*N
#define DD 256
#define HEADS 4
#define HD 1024       // HEADS*D
#define DSS 768
#define DTT 128
#define NE 131072     // raw edges
#define NEP (NE + BN) // + self loops
#define DEGCAP 256    // LDS-cached edges per node (max in-degree ~40 for this input)

typedef __hip_bfloat16 bf16;
typedef __attribute__((ext_vector_type(8))) short short8;   // 8 bf16 (4 VGPRs)
typedef __attribute__((ext_vector_type(4))) float floatx4;  // MFMA C/D

__device__ __forceinline__ float toF(bf16 x){ return __bfloat162float(x); }
__device__ __forceinline__ void stC(float* p, float v){ *p = v; }
__device__ __forceinline__ void stC(bf16* p, float v){ *p = __float2bfloat16(v); }
__device__ __forceinline__ float bf_lo(unsigned u){ return __uint_as_float(u << 16); }
__device__ __forceinline__ float bf_hi(unsigned u){ return __uint_as_float(u & 0xffff0000u); }

__device__ __forceinline__ float wredsum(float v){
  #pragma unroll
  for (int off = 32; off; off >>= 1) v += __shfl_xor(v, off);
  return v;
}
__device__ __forceinline__ float wredmax(float v){
  #pragma unroll
  for (int off = 32; off; off >>= 1) v = fmaxf(v, __shfl_xor(v, off));
  return v;
}

// transpose one 32x32 tile: dst[c][r] = bf16(src[r][c]) (whole block same branch)
__device__ __forceinline__ void dev_transpose(
    float tb[32][33], const float* __restrict__ src, bf16* __restrict__ dst,
    int R, int C, int bx, int by, int tid)
{
  int c0 = bx*32, r0 = by*32;
  int tr = tid >> 5, tc = tid & 31;
  #pragma unroll
  for (int i = 0; i < 4; i++)
    tb[tr + i*8][tc] = src[(size_t)(r0 + tr + i*8)*C + c0 + tc];
  __syncthreads();
  #pragma unroll
  for (int i = 0; i < 4; i++)
    dst[(size_t)(c0 + tr + i*8)*R + r0 + tc] = __float2bfloat16(tb[tc][tr + i*8]);
}

// ---------------------------------------------------------------------------
// prep1: ALL independent prep work in one launch, partitioned by block range.
//  [0,32)      textf/editp projections
//  [32,128)    WfullT (ws@wp fused weight, transposed bf16)
//  [128,6272)  structure_emb fp32->bf16
//  [6272,6528) g1_lin transpose -> g1T
//  [6528,6784) g2_lin transpose -> g2T
//  [6784,6848) cw1 transpose -> W2T[0:256]
//  [6848,6912) aw1 transpose -> W2T[256:512]
//  [6912,7040) WdT block-diag final weight + bias23
//  [7040,7072) CSR init + zero a_s/a_d accumulators + bias2 concat
// ---------------------------------------------------------------------------
__global__ __launch_bounds__(256) void prep1(
    const float* __restrict__ text_emb, const float* __restrict__ edit_emb,
    const float* __restrict__ wt, const float* __restrict__ bt,
    const float* __restrict__ we, const float* __restrict__ be,
    float* __restrict__ textf, float* __restrict__ editp,
    const float* __restrict__ wsm, const float* __restrict__ wp, bf16* __restrict__ WfT,
    const float* __restrict__ semb, bf16* __restrict__ sembB,
    const float* __restrict__ g1_lin, bf16* __restrict__ g1T,
    const float* __restrict__ g2_lin, bf16* __restrict__ g2T,
    const float* __restrict__ cw1, const float* __restrict__ aw1, bf16* __restrict__ W2T,
    const float* __restrict__ cw2, const float* __restrict__ cb2,
    const float* __restrict__ aw2, const float* __restrict__ ab2,
    bf16* __restrict__ WdT, float* __restrict__ bias23,
    int* __restrict__ counts, int* __restrict__ fc, float* __restrict__ zz,
    const float* __restrict__ cb1, const float* __restrict__ ab1, float* __restrict__ bias2)
{
  __shared__ float tpose[32][33];
  __shared__ float red[2][4][64];
  int blk = blockIdx.x, tid = threadIdx.x;
  if (blk < 32) {
    int b = blk & 7, l = tid & 63, qq = tid >> 6;
    int d = (blk >> 3)*64 + l;
    float tf = 0.f;
    for (int k = qq*32; k < qq*32 + 32; k++) tf += text_emb[b*DTT + k] * wt[(size_t)k*DD + d];
    float ep = 0.f;
    for (int k = qq*192; k < qq*192 + 192; k++) ep += edit_emb[b*DSS + k] * we[(size_t)k*DD + d];
    red[0][qq][l] = tf; red[1][qq][l] = ep;
    __syncthreads();
    if (tid < 64) {
      int dd = (blk >> 3)*64 + tid;
      textf[b*DD + dd] = red[0][0][tid]+red[0][1][tid]+red[0][2][tid]+red[0][3][tid] + bt[dd];
      editp[b*DD + dd] = red[1][0][tid]+red[1][1][tid]+red[1][2][tid]+red[1][3][tid] + be[dd];
    }
  } else if (blk < 128) {
    int k0 = (blk - 32)*8, d = tid;
    float acc[8] = {};
    for (int j = 0; j < DD; j++) {
      float wv = wp[(size_t)j*DD + d];
      #pragma unroll
      for (int kk = 0; kk < 8; kk++) acc[kk] += wsm[(size_t)(k0 + kk)*DD + j] * wv;
    }
    #pragma unroll
    for (int kk = 0; kk < 8; kk++) WfT[(size_t)d*DSS + k0 + kk] = __float2bfloat16(acc[kk]);
  } else if (blk < 6272) {
    int i = ((blk - 128)*256 + tid)*4;
    float4 v = *(const float4*)(semb + i);
    bf16 t4[4] = {__float2bfloat16(v.x), __float2bfloat16(v.y),
                  __float2bfloat16(v.z), __float2bfloat16(v.w)};
    *(uint2*)(sembB + i) = *(uint2*)t4;
  } else if (blk < 6528) {
    int lo = blk - 6272; dev_transpose(tpose, g1_lin, g1T, DD, HD, lo & 31, lo >> 5, tid);
  } else if (blk < 6784) {
    int lo = blk - 6528; dev_transpose(tpose, g2_lin, g2T, DD, HD, lo & 31, lo >> 5, tid);
  } else if (blk < 6848) {
    int lo = blk - 6784; dev_transpose(tpose, cw1, W2T, DD, DD, lo & 7, lo >> 3, tid);
  } else if (blk < 6912) {
    int lo = blk - 6848; dev_transpose(tpose, aw1, W2T + 65536, DD, DD, lo & 7, lo >> 3, tid);
  } else if (blk < 7040) {
    int idx = (blk - 6912)*256 + tid;     // 0..32767
    int n = idx >> 9, k = idx & 511;
    float v = 0.f;
    if (n < 3) { if (k < 256) v = cw2[(size_t)k*3 + n]; }
    else if (n < 23) { if (k >= 256) v = aw2[(size_t)(k - 256)*20 + (n - 3)]; }
    WdT[idx] = __float2bfloat16(v);
    if (idx < 64) bias23[idx] = idx < 3 ? cb2[idx] : (idx < 23 ? ab2[idx - 3] : 0.f);
  } else {
    int i = (blk - 7040)*256 + tid;       // 0..8191
    counts[i] = 1; fc[i] = 0;
    float4 z = make_float4(0.f, 0.f, 0.f, 0.f);
    #pragma unroll
    for (int j = 0; j < 4; j++) ((float4*)zz)[i*4 + j] = z;
    if (i < 256) bias2[i] = cb1[i];
    else if (i < 512) bias2[i] = ab1[i - 256];
  }
}

// ---------------------------------------------------------------------------
// prep2: vh projection + cvec + edge counting (all depend only on prep1)
//  [0,512) vh; [512,544) cvec; [544,1056) csr_count
// ---------------------------------------------------------------------------
__global__ __launch_bounds__(256) void prep2(
    const float* __restrict__ textf, const float* __restrict__ editp,
    const float* __restrict__ mha_iw, const float* __restrict__ mha_ib, float* __restrict__ vh,
    const float* __restrict__ bs, const float* __restrict__ wp, const float* __restrict__ bp,
    float* __restrict__ cvec,
    const int* __restrict__ ei, int* __restrict__ counts)
{
  __shared__ float red[4][64];
  int blk = blockIdx.x, tid = threadIdx.x;
  if (blk < 512) {
    int b = blk & 7, w = tid >> 6, l = tid & 63;
    int d = (blk >> 3)*4 + w;
    float p = 0.f;
    #pragma unroll
    for (int i = 0; i < 4; i++) p += textf[b*DD + l + 64*i] * mha_iw[(size_t)(512 + d)*DD + l + 64*i];
    p = wredsum(p);
    if (l == 0) vh[b*DD + d] = p + mha_ib[512 + d];
  } else if (blk < 544) {
    int lo = blk - 512;
    int b = lo & 7, l = tid & 63, qq = tid >> 6;
    int d = (lo >> 3)*64 + l;
    float cv = 0.f;
    for (int k = qq*64; k < qq*64 + 64; k++) cv += bs[k] * wp[(size_t)k*DD + d];
    for (int k = qq*64; k < qq*64 + 64; k++) cv += textf[b*DD + k] * wp[(size_t)(DD + k)*DD + d];
    for (int k = qq*64; k < qq*64 + 64; k++) cv += editp[b*DD + k] * wp[(size_t)(2*DD + k)*DD + d];
    red[qq][l] = cv;
    __syncthreads();
    if (tid < 64) {
      int dd = (lo >> 3)*64 + tid;
      cvec[b*DD + dd] = red[0][tid]+red[1][tid]+red[2][tid]+red[3][tid] + bp[dd] + editp[b*DD + dd];
    }
  } else {
    int e = (blk - 544)*256 + tid;
    if (e < NE) atomicAdd(&counts[ei[NE + e]], 1);
  }
}

// ---------------------------------------------------------------------------
// prep3 (1024 thr): mhavec projection [0,128) + CSR prefix scan [128]
// ---------------------------------------------------------------------------
__global__ __launch_bounds__(1024) void prep3(
    const float* __restrict__ vh, const float* __restrict__ mha_ow,
    const float* __restrict__ mha_ob, float* __restrict__ mhavec,
    const int* __restrict__ counts, int* __restrict__ offs)
{
  __shared__ int part[1024];
  int blk = blockIdx.x, t = threadIdx.x;
  if (blk < 128) {
    int b = blk >> 4, w16 = t >> 6, l = t & 63;
    int d = (blk & 15)*16 + w16;
    float p = 0.f;
    #pragma unroll
    for (int i = 0; i < 4; i++) p += vh[b*DD + l + 64*i] * mha_ow[(size_t)d*DD + l + 64*i];
    p = wredsum(p);
    if (l == 0) mhavec[b*DD + d] = p + mha_ob[d];
  } else {
    int local[8]; int sum = 0;
    #pragma unroll
    for (int i = 0; i < 8; i++) { local[i] = sum; sum += counts[t*8 + i]; }
    part[t] = sum;
    __syncthreads();
    for (int off = 1; off < 1024; off <<= 1) {
      int v = (t >= off) ? part[t - off] : 0;
      __syncthreads();
      part[t] += v;
      __syncthreads();
    }
    int base = (t == 0) ? 0 : part[t - 1];
    #pragma unroll
    for (int i = 0; i < 8; i++) offs[t*8 + i] = base + local[i];
    if (t == 1023) offs[BN] = part[1023];
  }
}

__global__ void csr_fill(const int* __restrict__ ei, const int* __restrict__ offs,
                         int* __restrict__ fc, int* __restrict__ csr)
{
  int idx = blockIdx.x*256 + threadIdx.x;
  if (idx < NE) {
    int sn = ei[idx], dn = ei[NE + idx];
    int p = offs[dn] + atomicAdd(&fc[dn], 1);
    csr[p] = sn;
  } else if (idx < NEP) {
    int i2 = idx - NE;
    int p = offs[i2] + atomicAdd(&fc[i2], 1);
    csr[p] = i2;
  }
}

// ---------------------------------------------------------------------------
// MFMA GEMM: C[M,N] = A[M,K] @ Bt[N,K]^T, bf16 in, fp32 acc, 64x64 tile.
// Optional fused epilogues: bias/rowvec/relu; GAT attention-score partials.
// ---------------------------------------------------------------------------
template<typename TC>
__global__ __launch_bounds__(256) void gemm_mfma(
    const bf16* __restrict__ A, const bf16* __restrict__ Bt, TC* __restrict__ C,
    int M, int N, int K,
    const float* __restrict__ bias, const float* __restrict__ rowvec, int relu,
    const float* __restrict__ atts, const float* __restrict__ attd,
    float* __restrict__ as_out, float* __restrict__ ad_out)
{
  __shared__ __align__(16) bf16 Asl[64*72];
  __shared__ __align__(16) bf16 Bsl[64*72];
  int tid = threadIdx.x;
  int w = tid >> 6, lane = tid & 63;
  int q = lane >> 4, mn = lane & 15;
  int row0 = blockIdx.y*64, col0 = blockIdx.x*64;
  int sr = tid >> 3, sc = tid & 7;
  floatx4 acc[4];
  #pragma unroll
  for (int t = 0; t < 4; t++) acc[t] = (floatx4){0.f, 0.f, 0.f, 0.f};

  for (int k0 = 0; k0 < K; k0 += 64) {
    uint4 a0 = *(const uint4*)(A  + (size_t)(row0 + sr)*K      + k0 + sc*8);
    uint4 a1 = *(const uint4*)(A  + (size_t)(row0 + 32 + sr)*K + k0 + sc*8);
    uint4 b0 = *(const uint4*)(Bt + (size_t)(col0 + sr)*K      + k0 + sc*8);
    uint4 b1 = *(const uint4*)(Bt + (size_t)(col0 + 32 + sr)*K + k0 + sc*8);
    __syncthreads();
    *(uint4*)&Asl[sr*72 + sc*8]        = a0;
    *(uint4*)&Asl[(sr + 32)*72 + sc*8] = a1;
    *(uint4*)&Bsl[sr*72 + sc*8]        = b0;
    *(uint4*)&Bsl[(sr + 32)*72 + sc*8] = b1;
    __syncthreads();
    #pragma unroll
    for (int kk = 0; kk < 64; kk += 32) {
      short8 af = *(const short8*)&Asl[(w*16 + mn)*72 + kk + q*8];
      #pragma unroll
      for (int t = 0; t < 4; t++) {
        short8 bfr = *(const short8*)&Bsl[(t*16 + mn)*72 + kk + q*8];
        acc[t] = __builtin_amdgcn_mfma_f32_16x16x32_bf16(af, bfr, acc[t], 0, 0, 0);
      }
    }
  }
  if (as_out) {   // fused GAT attention-score partials (head h = col0>>8)
    int h = col0 >> 8, cbase = col0 & 255;
    float ps[4] = {}, pd[4] = {};
    #pragma unroll
    for (int t = 0; t < 4; t++) {
      float av = atts[h*DD + cbase + t*16 + mn];
      float dv = attd[h*DD + cbase + t*16 + mn];
      #pragma unroll
      for (int rg = 0; rg < 4; rg++) {
        ps[rg] += acc[t][rg]*av;
        pd[rg] += acc[t][rg]*dv;
      }
    }
    #pragma unroll
    for (int rg = 0; rg < 4; rg++) {
      #pragma unroll
      for (int off = 1; off < 16; off <<= 1) {
        ps[rg] += __shfl_xor(ps[rg], off);
        pd[rg] += __shfl_xor(pd[rg], off);
      }
      if (mn == 0) {
        int r = row0 + w*16 + q*4 + rg;
        atomicAdd(&as_out[r*4 + h], ps[rg]);
        atomicAdd(&ad_out[r*4 + h], pd[rg]);
      }
    }
  }
  #pragma unroll
  for (int t = 0; t < 4; t++) {
    #pragma unroll
    for (int rg = 0; rg < 4; rg++) {
      int r = row0 + w*16 + q*4 + rg;
      int c = col0 + t*16 + mn;
      float v = acc[t][rg];
      if (bias)   v += bias[c];
      if (rowvec) v += rowvec[(size_t)(r >> 10)*N + c];
      if (relu)   v = fmaxf(v, 0.f);
      stC(&C[(size_t)r*N + c], v);
    }
  }
}

// ---------------------------------------------------------------------------
// final-head GEMM (K=512, N=64, block-diag Wd) + fused per-row softmax.
// Row r lives in the 16 lanes {q*16+mn}; 16-lane butterflies do the softmax.
// Writes coords (cols 0..2) and aa-probs (cols 3..22) straight to d_out.
// ---------------------------------------------------------------------------
__global__ __launch_bounds__(256) void gemm_fin(
    const bf16* __restrict__ A, const bf16* __restrict__ Bt,
    const float* __restrict__ bias, float* __restrict__ out)
{
  __shared__ __align__(16) bf16 Asl[64*72];
  __shared__ __align__(16) bf16 Bsl[64*72];
  const int K = 512;
  int tid = threadIdx.x;
  int w = tid >> 6, lane = tid & 63;
  int q = lane >> 4, mn = lane & 15;
  int row0 = blockIdx.x*64;
  int sr = tid >> 3, sc = tid & 7;
  floatx4 acc[4];
  #pragma unroll
  for (int t = 0; t < 4; t++) acc[t] = (floatx4){0.f, 0.f, 0.f, 0.f};
  for (int k0 = 0; k0 < K; k0 += 64) {
    uint4 a0 = *(const uint4*)(A  + (size_t)(row0 + sr)*K      + k0 + sc*8);
    uint4 a1 = *(const uint4*)(A  + (size_t)(row0 + 32 + sr)*K + k0 + sc*8);
    uint4 b0 = *(const uint4*)(Bt + (size_t)sr*K      + k0 + sc*8);
    uint4 b1 = *(const uint4*)(Bt + (size_t)(32 + sr)*K + k0 + sc*8);
    __syncthreads();
    *(uint4*)&Asl[sr*72 + sc*8]        = a0;
    *(uint4*)&Asl[(sr + 32)*72 + sc*8] = a1;
    *(uint4*)&Bsl[sr*72 + sc*8]        = b0;
    *(uint4*)&Bsl[(sr + 32)*72 + sc*8] = b1;
    __syncthreads();
    #pragma unroll
    for (int kk = 0; kk < 64; kk += 32) {
      short8 af = *(const short8*)&Asl[(w*16 + mn)*72 + kk + q*8];
      #pragma unroll
      for (int t = 0; t < 4; t++) {
        short8 bfr = *(const short8*)&Bsl[(t*16 + mn)*72 + kk + q*8];
        acc[t] = __builtin_amdgcn_mfma_f32_16x16x32_bf16(af, bfr, acc[t], 0, 0, 0);
      }
    }
  }
  #pragma unroll
  for (int rg = 0; rg < 4; rg++) {
    int r = row0 + w*16 + q*4 + rg;
    float mx = -1e30f;
    #pragma unroll
    for (int t = 0; t < 4; t++) {
      int c = t*16 + mn;
      float val = acc[t][rg] + bias[c];
      if (c >= 3 && c < 23) mx = fmaxf(mx, val);
    }
    #pragma unroll
    for (int off = 1; off < 16; off <<= 1) mx = fmaxf(mx, __shfl_xor(mx, off));
    float sum = 0.f;
    #pragma unroll
    for (int t = 0; t < 4; t++) {
      int c = t*16 + mn;
      float val = acc[t][rg] + bias[c];
      if (c >= 3 && c < 23) sum += expf(val - mx);
    }
    #pragma unroll
    for (int off = 1; off < 16; off <<= 1) sum += __shfl_xor(sum, off);
    float inv = 1.f / sum;
    #pragma unroll
    for (int t = 0; t < 2; t++) {
      int c = t*16 + mn;
      float val = acc[t][rg] + bias[c];
      if (c < 3) out[(size_t)r*3 + c] = val;
      else if (c < 23) out[24576 + (size_t)r*20 + (c - 3)] = expf(val - mx)*inv;
    }
  }
}

// ---------------------------------------------------------------------------
// GAT aggregation: block per dst node, wave per head; LDS-cached edge list +
// softmax weights. Epilogue: head-mean+bias+relu, then either +edit (layer 1)
// or fused comb (layer 2: 2-token global attention + mhavec). bf16 out.
// ---------------------------------------------------------------------------
__global__ __launch_bounds__(256) void gat_aggregate(
    const bf16* __restrict__ xw, const float* __restrict__ a_s, const float* __restrict__ a_d,
    const int* __restrict__ offs, const int* __restrict__ csr,
    const float* __restrict__ bias, const float* __restrict__ editadd,
    const float* __restrict__ ctext, const float* __restrict__ cedit,
    const float* __restrict__ cmha,
    bf16* __restrict__ xout)
{
  int i = blockIdx.x, t = threadIdx.x;
  int h = t >> 6, l = t & 63;
  int beg = offs[i], end = offs[i + 1], deg = end - beg;
  __shared__ float sacc[HD];
  __shared__ float sal[4][DEGCAP];
  __shared__ int   scsr[DEGCAP];
  float adh = a_d[i*4 + h];
  float mloc = -1e30f;
  for (int idx = l; idx < deg; idx += 64) {
    int sn = csr[beg + idx];
    if (h == 0 && idx < DEGCAP) scsr[idx] = sn;
    float al = a_s[sn*4 + h] + adh;
    al = al > 0.f ? al : 0.2f*al;
    if (idx < DEGCAP) sal[h][idx] = al;
    mloc = fmaxf(mloc, al);
  }
  float mh = wredmax(mloc);                     // finite: deg >= 1
  float sloc = 0.f;
  for (int idx = l; idx < deg; idx += 64) {
    float al;
    if (idx < DEGCAP) al = sal[h][idx];
    else {
      int sn = csr[beg + idx];
      al = a_s[sn*4 + h] + adh;
      al = al > 0.f ? al : 0.2f*al;
    }
    float wv = expf(al - mh);
    if (idx < DEGCAP) sal[h][idx] = wv;
    sloc += wv;
  }
  float inv = 1.f / wredsum(sloc);              // denom >= 1
  __syncthreads();
  const bf16* xbase = xw + h*DD + l*4;
  float acc0 = 0.f, acc1 = 0.f, acc2 = 0.f, acc3 = 0.f;
  int cached = deg < DEGCAP ? deg : DEGCAP;
  for (int idx = 0; idx < cached; idx++) {
    int sn = scsr[idx];
    float wv = sal[h][idx];
    uint2 u = *(const uint2*)(xbase + (size_t)sn*HD);
    acc0 += wv*bf_lo(u.x); acc1 += wv*bf_hi(u.x);
    acc2 += wv*bf_lo(u.y); acc3 += wv*bf_hi(u.y);
  }
  for (int idx = cached; idx < deg; idx++) {    // cold path (deg > DEGCAP)
    int sn = csr[beg + idx];
    float al = a_s[sn*4 + h] + adh;
    al = al > 0.f ? al : 0.2f*al;
    float wv = expf(al - mh);
    uint2 u = *(const uint2*)(xbase + (size_t)sn*HD);
    acc0 += wv*bf_lo(u.x); acc1 += wv*bf_hi(u.x);
    acc2 += wv*bf_lo(u.y); acc3 += wv*bf_hi(u.y);
  }
  sacc[h*DD + l*4 + 0] = acc0*inv;
  sacc[h*DD + l*4 + 1] = acc1*inv;
  sacc[h*DD + l*4 + 2] = acc2*inv;
  sacc[h*DD + l*4 + 3] = acc3*inv;
  __syncthreads();
  if (t < 64) {                                  // wave 0 only
    int b = i >> 10;
    float v[4], tx[4], ex[4];
    #pragma unroll
    for (int j = 0; j < 4; j++) {
      int d = t*4 + j;
      float x = 0.25f*(sacc[d] + sacc[DD + d] + sacc[2*DD + d] + sacc[3*DD + d]) + bias[d];
      v[j] = fmaxf(x, 0.f);                      // relu from reference
    }
    if (cmha) {
      // fused comb: node + softmax2(node.textf, node.editp)@[textf;editp] + mhavec
      float s0 = 0.f, s1 = 0.f;
      #pragma unroll
      for (int j = 0; j < 4; j++) {
        int d = t*4 + j;
        tx[j] = ctext[b*DD + d]; ex[j] = cedit[b*DD + d];
        s0 += v[j]*tx[j]; s1 += v[j]*ex[j];
      }
      s0 = wredsum(s0); s1 = wredsum(s1);
      float mm = fmaxf(s0, s1);
      float e0 = expf(s0 - mm), e1 = expf(s1 - mm);
      float inv2 = 1.f / (e0 + e1);
      float p0 = e0*inv2, p1 = e1*inv2;
      #pragma unroll
      for (int j = 0; j < 4; j++) {
        int d = t*4 + j;
        xout[(size_t)i*DD + d] = __float2bfloat16(v[j] + p0*tx[j] + p1*ex[j] + cmha[b*DD + d]);
      }
    } else {
      #pragma unroll
      for (int j = 0; j < 4; j++) {
        int d = t*4 + j;
        float x = v[j];
        if (editadd) x += editadd[b*DD + d];     // + edit_flat for next layer input
        xout[(size_t)i*DD + d] = __float2bfloat16(x);
      }
    }
  }
}

// ---------------------------------------------------------------------------
extern "C" void kernel_launch(void* const* d_in, const int* in_sizes, int n_in,
                              void* d_out, int out_size, void* d_ws, size_t ws_size,
                              hipStream_t stream)
{
  (void)in_sizes; (void)n_in; (void)out_size; (void)ws_size;
  const float* structure_emb = (const float*)d_in[0];
  const float* text_emb      = (const float*)d_in[1];
  const float* edit_emb      = (const float*)d_in[3];
  const float* ws_w    = (const float*)d_in[4];
  const float* bs_b    = (const float*)d_in[5];
  const float* wt_w    = (const float*)d_in[6];
  const float* bt_b    = (const float*)d_in[7];
  const float* we_w    = (const float*)d_in[8];
  const float* be_b    = (const float*)d_in[9];
  const float* wp_w    = (const float*)d_in[10];
  const float* bp_b    = (const float*)d_in[11];
  const float* g1_lin  = (const float*)d_in[12];
  const float* g1_as   = (const float*)d_in[13];
  const float* g1_ad   = (const float*)d_in[14];
  const float* g1_b    = (const float*)d_in[15];
  const float* g2_lin  = (const float*)d_in[16];
  const float* g2_as   = (const float*)d_in[17];
  const float* g2_ad   = (const float*)d_in[18];
  const float* g2_b    = (const float*)d_in[19];
  const float* mha_iw  = (const float*)d_in[20];
  const float* mha_ib  = (const float*)d_in[21];
  const float* mha_ow  = (const float*)d_in[22];
  const float* mha_ob  = (const float*)d_in[23];
  const float* cw1     = (const float*)d_in[24];
  const float* cb1     = (const float*)d_in[25];
  const float* cw2     = (const float*)d_in[26];
  const float* cb2     = (const float*)d_in[27];
  const float* aw1     = (const float*)d_in[28];
  const float* ab1     = (const float*)d_in[29];
  const float* aw2     = (const float*)d_in[30];
  const float* ab2     = (const float*)d_in[31];
  const int*  edge_index = (const int*)d_in[32];
  float* out = (float*)d_out;

  // --- workspace layout (~22 MB) ---
  char* p = (char*)d_ws;
  // 16 MB big region, time-multiplexed: sembB (12.6MB) -> xwb (16MB) -> h1b (8MB)
  bf16*  sembB = (bf16*)p;
  bf16*  xwb   = (bf16*)p;
  bf16*  h1b   = (bf16*)p;
  p += 16777216;
  bf16* bufB = (bf16*)p; p += 4194304;   // [8192][256] bf16: x0 -> x1e -> node2+comb
  bf16* g1T  = (bf16*)p; p += 524288;    // [1024][256]
  bf16* g2T  = (bf16*)p; p += 524288;
  bf16* W2T  = (bf16*)p; p += 262144;    // [512][256]: cw1T ++ aw1T
  bf16* WfT  = (bf16*)p; p += 393216;    // [256][768]
  bf16* WdT  = (bf16*)p; p += 65536;     // [64][512] block-diag final weight
  float* textf  = (float*)p; p += 8192;
  float* editp  = (float*)p; p += 8192;
  float* vhws   = (float*)p; p += 8192;
  float* mhavec = (float*)p; p += 8192;
  float* cvec   = (float*)p; p += 8192;
  float* bias2  = (float*)p; p += 2048;
  float* bias23 = (float*)p; p += 256;
  float* a_s1   = (float*)p; p += 131072;  // zz block: a_s1,a_d1,a_s2,a_d2
  float* a_d1   = (float*)p; p += 131072;
  float* a_s2   = (float*)p; p += 131072;
  float* a_d2   = (float*)p; p += 131072;
  int* counts = (int*)p; p += 32768;
  int* offs   = (int*)p; p += 32784;
  int* fc     = (int*)p; p += 32768;
  int* csr    = (int*)p; p += NEP*4;

  // 3 consolidated prep launches + csr_fill
  prep1<<<7072, 256, 0, stream>>>(
      text_emb, edit_emb, wt_w, bt_b, we_w, be_b, textf, editp,
      ws_w, wp_w, WfT, structure_emb, sembB,
      g1_lin, g1T, g2_lin, g2T, cw1, aw1, W2T,
      cw2, cb2, aw2, ab2, WdT, bias23,
      counts, fc, a_s1, cb1, ab1, bias2);
  prep2<<<1056, 256, 0, stream>>>(
      textf, editp, mha_iw, mha_ib, vhws, bs_b, wp_w, bp_b, cvec,
      edge_index, counts);
  prep3<<<129, 1024, 0, stream>>>(vhws, mha_ow, mha_ob, mhavec, counts, offs);
  csr_fill<<<(NEP + 255)/256, 256, 0, stream>>>(edge_index, offs, fc, csr);

  // x0 = semb @ Wfull + cvec[batch]  -> bufB (bf16)
  gemm_mfma<bf16><<<dim3(DD/64, BN/64), 256, 0, stream>>>(
      sembB, WfT, bufB, BN, DD, DSS, nullptr, cvec, 0,
      nullptr, nullptr, nullptr, nullptr);

  // GAT layer 1 (xw gemm + fused attention scores)
  gemm_mfma<bf16><<<dim3(HD/64, BN/64), 256, 0, stream>>>(
      bufB, g1T, xwb, BN, HD, DD, nullptr, nullptr, 0,
      g1_as, g1_ad, a_s1, a_d1);
  gat_aggregate<<<BN, 256, 0, stream>>>(xwb, a_s1, a_d1, offs, csr, g1_b, editp,
                                        nullptr, nullptr, nullptr, bufB);

  // GAT layer 2 (+ fused comb epilogue)
  gemm_mfma<bf16><<<dim3(HD/64, BN/64), 256, 0, stream>>>(
      bufB, g2T, xwb, BN, HD, DD, nullptr, nullptr, 0,
      g2_as, g2_ad, a_s2, a_d2);
  gat_aggregate<<<BN, 256, 0, stream>>>(xwb, a_s2, a_d2, offs, csr, g2_b, nullptr,
                                        textf, editp, mhavec, bufB);

  // combined head gemm -> h1b bf16 [8192][512] (xwb dead by now)
  gemm_mfma<bf16><<<dim3(512/64, BN/64), 256, 0, stream>>>(
      bufB, W2T, h1b, BN, 512, DD, bias2, nullptr, 1,
      nullptr, nullptr, nullptr, nullptr);

  // final projection + fused softmax -> d_out
  gemm_fin<<<BN/64, 256, 0, stream>>>(h1b, WdT, bias23, out);
}